// Round 4
// baseline (429.026 us; speedup 1.0000x reference)
//
#include <hip/hip_runtime.h>
#include <hip/hip_bf16.h>
#include <math.h>

// Problem constants (QwenAttention: B=2,S=2048,E=2048,H=16,KV=4,D=128)
#define BB 2
#define SS 2048
#define EE 2048
#define HH 16
#define KVH 4
#define DD 128
#define QTILES 32   // S / 64

typedef short short8 __attribute__((ext_vector_type(8)));
typedef float f32x4 __attribute__((ext_vector_type(4)));

__device__ __forceinline__ unsigned int f2bf1(float x) {
    union { float f; unsigned int u; } v; v.f = x;
    return (v.u + 0x7FFFu + ((v.u >> 16) & 1u)) >> 16;  // RNE bf16
}
__device__ __forceinline__ unsigned int packbf(float a, float b) {
    return f2bf1(a) | (f2bf1(b) << 16);
}
// async global->LDS, 16B per lane; LDS dest = wave-uniform base + lane*16
__device__ __forceinline__ void gl_lds16(const void* g, void* l) {
    __builtin_amdgcn_global_load_lds(
        (const __attribute__((address_space(1))) unsigned int*)g,
        (__attribute__((address_space(3))) unsigned int*)l,
        16, 0, 0);
}

// ---------------------------------------------------------------------------
// Fused fp32->bf16 conversion of all inputs + bias concat + RoPE cos/sin
// table, one launch. Segments in float4 units: x | Wq | Wk | Wv | Wo |
// biases(fp32) | rope table (cos[2048][64], sin[2048][64] f32).
// ---------------------------------------------------------------------------
__global__ __launch_bounds__(256) void cvt_all_kernel(
    const float* __restrict__ x,  const float* __restrict__ Wq,
    const float* __restrict__ Wk, const float* __restrict__ Wv,
    const float* __restrict__ Wo, const float* __restrict__ bq,
    const float* __restrict__ bk, const float* __restrict__ bv,
    unsigned short* __restrict__ xb, unsigned short* __restrict__ wqkv,
    unsigned short* __restrict__ wob, float* __restrict__ bqkv,
    float* __restrict__ rtab)
{
    long id = (long)blockIdx.x * 256 + threadIdx.x;
    const float* src; unsigned short* dst; long j;
    if (id < 2097152)      { j = id;           src = x;  dst = xb; }
    else if (id < 3145728) { j = id - 2097152; src = Wq; dst = wqkv; }
    else if (id < 3407872) { j = id - 3145728; src = Wk; dst = wqkv + 4194304; }
    else if (id < 3670016) { j = id - 3407872; src = Wv; dst = wqkv + 5242880; }
    else if (id < 4718592) { j = id - 3670016; src = Wo; dst = wob; }
    else if (id < 4719360) {
        long c = (id - 4718592) * 4;
#pragma unroll
        for (int e = 0; e < 4; ++e) {
            long cc = c + e;
            bqkv[cc] = (cc < 2048) ? bq[cc] : (cc < 2560 ? bk[cc - 2048] : bv[cc - 2560]);
        }
        return;
    } else if (id < 4850432) {
        // rope table: one sincos per (s, d) entry
        long e = id - 4719360;            // 0 .. 131071
        int sg = (int)(e >> 6);           // position 0..2047
        int dg = (int)(e & 63);           // freq index 0..63
        float inv_freq = expf(-(float)dg * (logf(10000.0f) / 64.0f));
        float fr = (float)sg * inv_freq;
        rtab[e]          = cosf(fr);
        rtab[131072 + e] = sinf(fr);
        return;
    } else return;
    float4 f = ((const float4*)src)[j];
    ((uint2*)dst)[j] = make_uint2(packbf(f.x, f.y), packbf(f.z, f.w));
}

// ---------------------------------------------------------------------------
// m97-style bf16 MFMA GEMM: C[M,N] = A[M,K] @ W[N,K]^T + bias[N]
// 128x128 tile, BK=32, 256 threads = 4 waves (2x2), 4x4 MFMA tiles per wave.
// ---------------------------------------------------------------------------
template <bool OUT_BF16>
__global__ __launch_bounds__(256) void gemm_mfma_kernel(
    const unsigned short* __restrict__ A, const unsigned short* __restrict__ W,
    const float* __restrict__ bias, void* __restrict__ Cout,
    int M, int N, int K)
{
    __shared__ unsigned short As[128 * 32];
    __shared__ unsigned short Bs[128 * 32];

    const int tid  = threadIdx.x;
    const int w    = tid >> 6;
    const int lane = tid & 63;
    const int quad = lane >> 4;
    const int l16  = lane & 15;
    const int wr   = w >> 1, wc = w & 1;
    const int m0 = blockIdx.y * 128, n0 = blockIdx.x * 128;

    f32x4 acc[4][4];
#pragma unroll
    for (int i = 0; i < 4; ++i)
#pragma unroll
        for (int j = 0; j < 4; ++j) acc[i][j] = (f32x4){0.f, 0.f, 0.f, 0.f};

    const unsigned short* Ag = A + (size_t)(m0 + w * 32 + (lane >> 2)) * K + (lane & 3) * 8;
    const unsigned short* Wg = W + (size_t)(n0 + w * 32 + (lane >> 2)) * K + (lane & 3) * 8;
    unsigned short* AsB = &As[(w * 32) * 32];
    unsigned short* BsB = &Bs[(w * 32) * 32];

    for (int k0 = 0; k0 < K; k0 += 32) {
        gl_lds16(Ag + k0, AsB);
        gl_lds16(Ag + k0 + (size_t)16 * K, AsB + 16 * 32);
        gl_lds16(Wg + k0, BsB);
        gl_lds16(Wg + k0 + (size_t)16 * K, BsB + 16 * 32);
        __syncthreads();

        short8 a_f[4], b_f[4];
#pragma unroll
        for (int i = 0; i < 4; ++i)
            a_f[i] = *(const short8*)&As[(wr * 64 + i * 16 + l16) * 32 + quad * 8];
#pragma unroll
        for (int j = 0; j < 4; ++j)
            b_f[j] = *(const short8*)&Bs[(wc * 64 + j * 16 + l16) * 32 + quad * 8];
#pragma unroll
        for (int i = 0; i < 4; ++i)
#pragma unroll
            for (int j = 0; j < 4; ++j)
                acc[i][j] = __builtin_amdgcn_mfma_f32_16x16x32_bf16(a_f[i], b_f[j], acc[i][j], 0, 0, 0);
        __syncthreads();
    }

    float bj[4];
#pragma unroll
    for (int j = 0; j < 4; ++j)
        bj[j] = bias ? bias[n0 + wc * 64 + j * 16 + l16] : 0.0f;
#pragma unroll
    for (int i = 0; i < 4; ++i) {
#pragma unroll
        for (int r = 0; r < 4; ++r) {
            size_t row = m0 + wr * 64 + i * 16 + quad * 4 + r;
#pragma unroll
            for (int j = 0; j < 4; ++j) {
                size_t col = n0 + wc * 64 + j * 16 + l16;
                float val = acc[i][j][r] + bj[j];
                if (OUT_BF16)
                    ((unsigned short*)Cout)[row * N + col] = (unsigned short)f2bf1(val);
                else
                    ((float*)Cout)[row * N + col] = val;
            }
        }
    }
}

// ---------------------------------------------------------------------------
// RoPE on bf16 qkv buffer [M, 3072] (q cols 0..2047, k cols 2048..2559).
// Table-based: cos/sin from precomputed [2048][64] f32 tables (no device
// trig in hot path). One block per row, 256 threads x 5 pairs.
// ---------------------------------------------------------------------------
__global__ __launch_bounds__(256) void rope_kernel(
    unsigned short* __restrict__ qkv,
    const float* __restrict__ ctab, const float* __restrict__ stab)
{
    const int m = blockIdx.x;          // row in [0, B*S)
    const int s = m & (SS - 1);
    unsigned short* p = qkv + (size_t)m * 3072;
    const float* cr = ctab + s * 64;
    const float* sr = stab + s * 64;
#pragma unroll
    for (int it = 0; it < 5; ++it) {
        int idx = threadIdx.x + it * 256;   // 0..1279 : 20 heads x 64 pairs
        int hh = idx >> 6;
        int d  = idx & 63;
        int cb = (hh < 16) ? hh * 128 : 2048 + (hh - 16) * 128;
        float c  = cr[d];
        float sn = sr[d];
        union { unsigned int u; float f; } x1, x2;
        x1.u = ((unsigned int)p[cb + d]) << 16;
        x2.u = ((unsigned int)p[cb + d + 64]) << 16;
        p[cb + d]      = (unsigned short)f2bf1(x1.f * c - x2.f * sn);
        p[cb + d + 64] = (unsigned short)f2bf1(x2.f * c + x1.f * sn);
    }
}

// ---------------------------------------------------------------------------
// Flash attention, bf16, MFMA 16x16x32, XOR-swizzled LDS (conflict-free),
// SPLIT-KV occupancy restructure:
//   - qt<16 : one block per 64-row q-tile (1..16 KV-units), final output.
//   - qt>=16: TWO blocks per q-tile, each half the KV range (8..16 units),
//     writing unnormalized f32 partials (O, m, l); attn_merge_kernel combines.
//   - grid 48x16x2 = 1536 blocks (> 1024 resident slots -> backfill absorbs
//     the work spread; max block 16 units ~= ideal slot load 16.5).
//   - single-buffered K/V + Ps = 40 KB LDS -> 4 blocks/CU = 4 waves/SIMD
//     (vs 2 before). VGPR stays ~96-112 with (256,2); NEVER (256,4): forces
//     64 VGPR + scratch spill (measured 358 us, round 1).
// qkv: [B*S, 3072] (q: h*128, k: 2048+kv*128, v: 2560+kv*128); o: [B*S, 2048].
// Swizzle keys: K/V chunk' = chunk ^ ((row + (row>>4)) & 7) at 16B-chunk
// granularity; P chunk' = chunk ^ ((row>>2) ^ ((row&3)<<1)).
// ---------------------------------------------------------------------------
__global__ __launch_bounds__(256, 2) void attn_mfma_kernel(
    const unsigned short* __restrict__ qkv, unsigned short* __restrict__ o,
    float* __restrict__ Opart, float* __restrict__ mlpart)
{
    __shared__ unsigned int Ks_u[64 * 64];     // 16 KB
    __shared__ unsigned int Vs_u[128 * 32];    // 16 KB
    __shared__ unsigned short Ps[4][16 * 64];  // 8 KB, per-wave

    const int tid  = threadIdx.x;
    const int w    = tid >> 6;
    const int lane = tid & 63;
    const int quad = lane >> 4;
    const int l16  = lane & 15;
    const int h     = blockIdx.y;
    const int b     = blockIdx.z;
    const int kv    = h >> 2;       // G = 4

    // ---- block -> (q-tile, KV chunk) mapping ----
    const int x = blockIdx.x;       // 0..47
    int qt, tbeg, tend, nc, ch;
    if (x < 16) {
        qt = x; tbeg = 0; tend = qt + 1; nc = 1; ch = 0;
    } else {
        int i = x - 16;
        qt = 16 + (i >> 1);
        ch = i & 1;
        int len = qt + 1;
        int half = (len + 1) >> 1;
        tbeg = ch ? half : 0;
        tend = ch ? len : half;
        nc = 2;
    }
    const int q0 = qt * 64;

    const float k2 = 0.12752789744920764f;  // (1/sqrt(128)) * log2(e)

    const unsigned short* kbase = qkv + (size_t)b * SS * 3072 + 2048 + kv * 128;
    const unsigned short* vbase = kbase + 512;

    const int kc  = tid & 15;          // K chunk (8 dims)
    const int kp0 = tid >> 4;          // K row base 0..15
    const int vpp = tid >> 3;          // V pos-pair 0..31
    const int vd0 = (tid & 7) * 16;    // V d-segment base

    unsigned int* Kb = Ks_u;
    unsigned int* Vb = Vs_u;

    // ---- Q A-frags ----
    short8 qf[4];
    {
        const unsigned short* qp = qkv + (size_t)(b * SS + q0 + w * 16 + l16) * 3072 + h * 128 + quad * 8;
#pragma unroll
        for (int ks = 0; ks < 4; ++ks)
            qf[ks] = *(const short8*)(qp + ks * 32);
    }

    // ---- prefetch first tile into regs ----
    uint4 kpre[4], vpa[2], vpb[2];
    {
        const unsigned short* kg = kbase + (size_t)(tbeg * 64 + kp0) * 3072 + kc * 8;
#pragma unroll
        for (int rr = 0; rr < 4; ++rr)
            kpre[rr] = *(const uint4*)(kg + (size_t)rr * 16 * 3072);
        const unsigned short* vg = vbase + (size_t)(tbeg * 64 + 2 * vpp) * 3072 + vd0;
        vpa[0] = *(const uint4*)(vg);
        vpa[1] = *(const uint4*)(vg + 8);
        vpb[0] = *(const uint4*)(vg + 3072);
        vpb[1] = *(const uint4*)(vg + 3072 + 8);
    }

    float m_r[4], l_r[4];
    f32x4 Oacc[8];
#pragma unroll
    for (int r = 0; r < 4; ++r) { m_r[r] = -1e30f; l_r[r] = 0.0f; }
#pragma unroll
    for (int ot = 0; ot < 8; ++ot) Oacc[ot] = (f32x4){0.f, 0.f, 0.f, 0.f};

    for (int t = tbeg; t < tend; ++t) {
        __syncthreads();   // all waves finished reading LDS from prev iter

        // ---- staged regs -> LDS (swizzled, conflict-free) ----
#pragma unroll
        for (int rr = 0; rr < 4; ++rr) {
            int pos = kp0 + rr * 16;
            int key = (kp0 + rr) & 7;           // (pos + (pos>>4)) & 7
            *(uint4*)&Kb[pos * 64 + (kc ^ key) * 4] = kpre[rr];
        }
        {
            const unsigned int* pa = (const unsigned int*)vpa;
            const unsigned int* pb = (const unsigned int*)vpb;
#pragma unroll
            for (int j = 0; j < 8; ++j) {
                unsigned lo = __builtin_amdgcn_perm(pb[j], pa[j], 0x05040100);
                unsigned hi = __builtin_amdgcn_perm(pb[j], pa[j], 0x07060302);
                int d0 = vd0 + 2 * j;
                int g  = d0 >> 4;               // same for d0 and d0+1
                int k0 = (d0 + g) & 7;
                int k1 = (d0 + 1 + g) & 7;
                Vb[d0 * 32 + (((vpp >> 2) ^ k0) & 7) * 4 + (vpp & 3)] = lo;
                Vb[(d0 + 1) * 32 + (((vpp >> 2) ^ k1) & 7) * 4 + (vpp & 3)] = hi;
            }
        }

        // ---- prefetch tile t+1 (latency hidden under compute) ----
        if (t + 1 < tend) {
            const unsigned short* kg = kbase + (size_t)((t + 1) * 64 + kp0) * 3072 + kc * 8;
#pragma unroll
            for (int rr = 0; rr < 4; ++rr)
                kpre[rr] = *(const uint4*)(kg + (size_t)rr * 16 * 3072);
            const unsigned short* vg = vbase + (size_t)((t + 1) * 64 + 2 * vpp) * 3072 + vd0;
            vpa[0] = *(const uint4*)(vg);
            vpa[1] = *(const uint4*)(vg + 8);
            vpb[0] = *(const uint4*)(vg + 3072);
            vpb[1] = *(const uint4*)(vg + 3072 + 8);
        }
        __syncthreads();   // staged writes visible to all waves

        // ---- S = Q @ K^T (16x64 per wave), raw scores ----
        f32x4 S[4];
#pragma unroll
        for (int ct = 0; ct < 4; ++ct) {
            f32x4 s = (f32x4){0.f, 0.f, 0.f, 0.f};
            const int row = ct * 16 + l16;
            const int key = (l16 + ct) & 7;     // (pos + (pos>>4)) & 7
#pragma unroll
            for (int ks = 0; ks < 4; ++ks) {
                short8 kf = *(const short8*)&Kb[row * 64 + ((ks * 4 + quad) ^ key) * 4];
                s = __builtin_amdgcn_mfma_f32_16x16x32_bf16(qf[ks], kf, s, 0, 0, 0);
            }
            S[ct] = s;
        }

        // ---- causal mask (diagonal tile only; only last chunk reaches it) ----
        if (t == qt) {
            const int rowloc = w * 16 + quad * 4;
#pragma unroll
            for (int ct = 0; ct < 4; ++ct)
#pragma unroll
                for (int r = 0; r < 4; ++r)
                    if (ct * 16 + l16 > rowloc + r) S[ct][r] = -1e30f;
        }

        // ---- online softmax (scale folded into exp2) ----
#pragma unroll
        for (int r = 0; r < 4; ++r) {
            float c0 = fmaxf(fmaxf(S[0][r], S[1][r]), fmaxf(S[2][r], S[3][r]));
            c0 = fmaxf(c0, __shfl_xor(c0, 1));
            c0 = fmaxf(c0, __shfl_xor(c0, 2));
            c0 = fmaxf(c0, __shfl_xor(c0, 4));
            c0 = fmaxf(c0, __shfl_xor(c0, 8));
            float mnew = fmaxf(m_r[r], c0);
            float alpha = exp2f((m_r[r] - mnew) * k2);
            m_r[r] = mnew;
            float mh = mnew * k2;
            float rs = 0.0f;
            const int prow = quad * 4 + r;
            const int pkey = (prow >> 2) ^ ((prow & 3) << 1);
#pragma unroll
            for (int ct = 0; ct < 4; ++ct) {
                float p = exp2f(S[ct][r] * k2 - mh);
                rs += p;
                int chunk = ct * 2 + (l16 >> 3);
                union { float f; unsigned u; } pu; pu.f = p;
                Ps[w][prow * 64 + (chunk ^ pkey) * 8 + (l16 & 7)] =
                    (unsigned short)((pu.u + 0x8000u) >> 16);
            }
            rs += __shfl_xor(rs, 1);
            rs += __shfl_xor(rs, 2);
            rs += __shfl_xor(rs, 4);
            rs += __shfl_xor(rs, 8);
            l_r[r] = l_r[r] * alpha + rs;
#pragma unroll
            for (int ot = 0; ot < 8; ++ot) Oacc[ot][r] *= alpha;
        }

        // ---- O += P @ V ----
        {
            const int pkeyr = (l16 >> 2) ^ ((l16 & 3) << 1);
            short8 pf0 = *(const short8*)&Ps[w][l16 * 64 + (quad ^ pkeyr) * 8];
            short8 pf1 = *(const short8*)&Ps[w][l16 * 64 + ((4 + quad) ^ pkeyr) * 8];
#pragma unroll
            for (int ot = 0; ot < 8; ++ot) {
                const int d = ot * 16 + l16;
                const int vkey = (l16 + ot) & 7;    // (d + (d>>4)) & 7
                short8 v0 = *(const short8*)&Vb[d * 32 + (quad ^ vkey) * 4];
                Oacc[ot] = __builtin_amdgcn_mfma_f32_16x16x32_bf16(pf0, v0, Oacc[ot], 0, 0, 0);
                short8 v1 = *(const short8*)&Vb[d * 32 + ((4 + quad) ^ vkey) * 4];
                Oacc[ot] = __builtin_amdgcn_mfma_f32_16x16x32_bf16(pf1, v1, Oacc[ot], 0, 0, 0);
            }
        }
    }

    if (nc == 1) {
        // ---- final output: normalize, bf16 store to [B*S, 2048] ----
        float inv[4];
#pragma unroll
        for (int r = 0; r < 4; ++r) inv[r] = 1.0f / l_r[r];
        const int orow0 = q0 + w * 16 + quad * 4;
        unsigned short* ob = o + (size_t)(b * SS + orow0) * 2048 + h * 128 + l16;
#pragma unroll
        for (int r = 0; r < 4; ++r)
#pragma unroll
            for (int ot = 0; ot < 8; ++ot)
                ob[(size_t)r * 2048 + ot * 16] = (unsigned short)f2bf1(Oacc[ot][r] * inv[r]);
    } else {
        // ---- partial output: unnormalized f32 O + (m, l) per row ----
        const int pidx = (((b * HH + h) * 16) + (qt - 16)) * 2 + ch;
        float* Op = Opart + (size_t)pidx * (64 * 128);
        const int rowloc0 = w * 16 + quad * 4;
#pragma unroll
        for (int r = 0; r < 4; ++r)
#pragma unroll
            for (int ot = 0; ot < 8; ++ot)
                Op[(size_t)(rowloc0 + r) * 128 + ot * 16 + l16] = Oacc[ot][r];
        if (l16 == 0) {
            float* mlp = mlpart + (size_t)pidx * 128;
#pragma unroll
            for (int r = 0; r < 4; ++r) {
                mlp[rowloc0 + r]      = m_r[r];
                mlp[64 + rowloc0 + r] = l_r[r];
            }
        }
    }
}

// ---------------------------------------------------------------------------
// Merge the two KV-chunk partials per q-tile (qt >= 16) into final bf16 out.
// grid (16, H, B); 256 threads: group g = tid>>6 covers rows g+4*it,
// lane c = tid&63 covers cols 2c, 2c+1 -> coalesced f32 loads + u32 stores.
// ---------------------------------------------------------------------------
__global__ __launch_bounds__(256) void attn_merge_kernel(
    const float* __restrict__ Opart, const float* __restrict__ mlpart,
    unsigned short* __restrict__ o)
{
    const float k2 = 0.12752789744920764f;
    const int qt = 16 + blockIdx.x;
    const int h  = blockIdx.y;
    const int b  = blockIdx.z;
    const int pbase = (((b * HH + h) * 16) + (qt - 16)) * 2;
    const float* O0  = Opart + (size_t)pbase * (64 * 128);
    const float* O1  = O0 + 64 * 128;
    const float* ml0 = mlpart + (size_t)pbase * 128;
    const float* ml1 = ml0 + 128;

    const int g = threadIdx.x >> 6;     // 0..3
    const int c = threadIdx.x & 63;     // col pair index

#pragma unroll
    for (int it = 0; it < 16; ++it) {
        int row = g + it * 4;
        float m0 = ml0[row], m1 = ml1[row];
        float l0 = ml0[64 + row], l1 = ml1[64 + row];
        float M  = fmaxf(m0, m1);
        float w0 = exp2f((m0 - M) * k2);
        float w1 = exp2f((m1 - M) * k2);
        float inv = 1.0f / (w0 * l0 + w1 * l1);
        const float* p0 = O0 + row * 128 + c * 2;
        const float* p1 = O1 + row * 128 + c * 2;
        float a = (w0 * p0[0] + w1 * p1[0]) * inv;
        float bv2 = (w0 * p0[1] + w1 * p1[1]) * inv;
        unsigned int* ob = (unsigned int*)(o + (size_t)(b * SS + qt * 64 + row) * 2048 + h * 128) + c;
        *ob = packbf(a, bv2);
    }
}

// ---------------------------------------------------------------------------
extern "C" void kernel_launch(void* const* d_in, const int* in_sizes, int n_in,
                              void* d_out, int out_size, void* d_ws, size_t ws_size,
                              hipStream_t stream)
{
    const float* x  = (const float*)d_in[0];
    const float* Wq = (const float*)d_in[1];
    const float* bq = (const float*)d_in[2];
    const float* Wk = (const float*)d_in[3];
    const float* bk = (const float*)d_in[4];
    const float* Wv = (const float*)d_in[5];
    const float* bv = (const float*)d_in[6];
    const float* Wo = (const float*)d_in[7];
    float* out = (float*)d_out;

    const int M = BB * SS;  // 4096
    char* wsb = (char*)d_ws;
    unsigned short* xb   = (unsigned short*)wsb;  wsb += (size_t)M * EE * 2;        // 16.8 MB
    unsigned short* wqkv = (unsigned short*)wsb;  wsb += (size_t)3072 * EE * 2;     // 12.6 MB
    unsigned short* wob  = (unsigned short*)wsb;  wsb += (size_t)EE * EE * 2;       //  8.4 MB
    unsigned short* qkvb = (unsigned short*)wsb;  wsb += (size_t)M * 3072 * 2;      // 25.2 MB
    unsigned short* abb  = (unsigned short*)wsb;  wsb += (size_t)M * 2048 * 2;      // 16.8 MB
    float* bqkv = (float*)wsb;                    wsb += 4096 * 4;                  // 16 KB (2560 used)
    float* rtab = (float*)wsb;                    wsb += (size_t)2 * 131072 * 4;    // 1 MB rope table
    float* Opart = (float*)wsb;                   wsb += (size_t)1024 * 64 * 128 * 4; // 33.6 MB partial O
    float* mlpart = (float*)wsb;                  // 0.5 MB (1024 * 128 f32)

    // one fused conversion launch (x, Wq, Wk, Wv, Wo, biases, rope table)
    cvt_all_kernel<<<18947, 256, 0, stream>>>(x, Wq, Wk, Wv, Wo, bq, bk, bv,
                                              xb, wqkv, wob, bqkv, rtab);

    // fused QKV projection: [M,3072] = xb @ wqkv^T + bqkv (bf16 out)
    gemm_mfma_kernel<true><<<dim3(3072 / 128, M / 128), 256, 0, stream>>>(
        xb, wqkv, bqkv, qkvb, M, 3072, EE);

    // RoPE on q and k heads, table-based, one block per row
    rope_kernel<<<M, 256, 0, stream>>>(qkvb, rtab, rtab + 131072);

    // flash attention (split-KV) -> abb (bf16) + partials for qt>=16
    attn_mfma_kernel<<<dim3(48, HH, BB), 256, 0, stream>>>(qkvb, abb, Opart, mlpart);

    // combine split-KV partials for qt>=16
    attn_merge_kernel<<<dim3(16, HH, BB), 256, 0, stream>>>(Opart, mlpart, abb);

    // output projection: out = abb @ wob^T (fp32 out)
    gemm_mfma_kernel<false><<<dim3(EE / 128, M / 128), 256, 0, stream>>>(
        abb, wob, nullptr, out, M, EE, 2048);
}

// Round 6
// 398.590 us; speedup vs baseline: 1.0764x; 1.0764x over previous
//
#include <hip/hip_runtime.h>
#include <hip/hip_bf16.h>
#include <math.h>

// Problem constants (QwenAttention: B=2,S=2048,E=2048,H=16,KV=4,D=128)
#define BB 2
#define SS 2048
#define EE 2048
#define HH 16
#define KVH 4
#define DD 128
#define QTILES 32   // S / 64

typedef short short8 __attribute__((ext_vector_type(8)));
typedef float f32x4 __attribute__((ext_vector_type(4)));

__device__ __forceinline__ unsigned int f2bf1(float x) {
    union { float f; unsigned int u; } v; v.f = x;
    return (v.u + 0x7FFFu + ((v.u >> 16) & 1u)) >> 16;  // RNE bf16
}
__device__ __forceinline__ unsigned int packbf(float a, float b) {
    return f2bf1(a) | (f2bf1(b) << 16);
}
// async global->LDS, 16B per lane; LDS dest = wave-uniform base + lane*16
__device__ __forceinline__ void gl_lds16(const void* g, void* l) {
    __builtin_amdgcn_global_load_lds(
        (const __attribute__((address_space(1))) unsigned int*)g,
        (__attribute__((address_space(3))) unsigned int*)l,
        16, 0, 0);
}

// ---------------------------------------------------------------------------
// Fused fp32->bf16 conversion of all inputs + bias concat + RoPE cos/sin
// table, one launch. Segments in float4 units: x | Wq | Wk | Wv | Wo |
// biases(fp32) | rope table (cos[2048][64], sin[2048][64] f32).
// ---------------------------------------------------------------------------
__global__ __launch_bounds__(256) void cvt_all_kernel(
    const float* __restrict__ x,  const float* __restrict__ Wq,
    const float* __restrict__ Wk, const float* __restrict__ Wv,
    const float* __restrict__ Wo, const float* __restrict__ bq,
    const float* __restrict__ bk, const float* __restrict__ bv,
    unsigned short* __restrict__ xb, unsigned short* __restrict__ wqkv,
    unsigned short* __restrict__ wob, float* __restrict__ bqkv,
    float* __restrict__ rtab)
{
    long id = (long)blockIdx.x * 256 + threadIdx.x;
    const float* src; unsigned short* dst; long j;
    if (id < 2097152)      { j = id;           src = x;  dst = xb; }
    else if (id < 3145728) { j = id - 2097152; src = Wq; dst = wqkv; }
    else if (id < 3407872) { j = id - 3145728; src = Wk; dst = wqkv + 4194304; }
    else if (id < 3670016) { j = id - 3407872; src = Wv; dst = wqkv + 5242880; }
    else if (id < 4718592) { j = id - 3670016; src = Wo; dst = wob; }
    else if (id < 4719360) {
        long c = (id - 4718592) * 4;
#pragma unroll
        for (int e = 0; e < 4; ++e) {
            long cc = c + e;
            bqkv[cc] = (cc < 2048) ? bq[cc] : (cc < 2560 ? bk[cc - 2048] : bv[cc - 2560]);
        }
        return;
    } else if (id < 4850432) {
        // rope table: one sincos per (s, d) entry
        long e = id - 4719360;            // 0 .. 131071
        int sg = (int)(e >> 6);           // position 0..2047
        int dg = (int)(e & 63);           // freq index 0..63
        float inv_freq = expf(-(float)dg * (logf(10000.0f) / 64.0f));
        float fr = (float)sg * inv_freq;
        rtab[e]          = cosf(fr);
        rtab[131072 + e] = sinf(fr);
        return;
    } else return;
    float4 f = ((const float4*)src)[j];
    ((uint2*)dst)[j] = make_uint2(packbf(f.x, f.y), packbf(f.z, f.w));
}

// ---------------------------------------------------------------------------
// m97-style bf16 MFMA GEMM: C[M,N] = A[M,K] @ W[N,K]^T + bias[N]
// 128x128 tile, BK=32, 256 threads = 4 waves (2x2), 4x4 MFMA tiles per wave.
// XCD-chunked blockIdx swizzle (T1): wg i lands on XCD i%8, so give each
// XCD a contiguous chunk of tiles -> A/B panel reuse stays in its L2.
// Requires nwg % 8 == 0 (768 and 512 here: both OK).
// ---------------------------------------------------------------------------
template <bool OUT_BF16>
__global__ __launch_bounds__(256) void gemm_mfma_kernel(
    const unsigned short* __restrict__ A, const unsigned short* __restrict__ W,
    const float* __restrict__ bias, void* __restrict__ Cout,
    int M, int N, int K)
{
    __shared__ unsigned short As[128 * 32];
    __shared__ unsigned short Bs[128 * 32];

    const int tid  = threadIdx.x;
    const int w    = tid >> 6;
    const int lane = tid & 63;
    const int quad = lane >> 4;
    const int l16  = lane & 15;
    const int wr   = w >> 1, wc = w & 1;

    const int bid = blockIdx.y * gridDim.x + blockIdx.x;
    const int cpx = (gridDim.x * gridDim.y) >> 3;
    const int swz = (bid & 7) * cpx + (bid >> 3);
    const int m0 = (swz / gridDim.x) * 128;
    const int n0 = (swz % gridDim.x) * 128;

    f32x4 acc[4][4];
#pragma unroll
    for (int i = 0; i < 4; ++i)
#pragma unroll
        for (int j = 0; j < 4; ++j) acc[i][j] = (f32x4){0.f, 0.f, 0.f, 0.f};

    const unsigned short* Ag = A + (size_t)(m0 + w * 32 + (lane >> 2)) * K + (lane & 3) * 8;
    const unsigned short* Wg = W + (size_t)(n0 + w * 32 + (lane >> 2)) * K + (lane & 3) * 8;
    unsigned short* AsB = &As[(w * 32) * 32];
    unsigned short* BsB = &Bs[(w * 32) * 32];

    for (int k0 = 0; k0 < K; k0 += 32) {
        gl_lds16(Ag + k0, AsB);
        gl_lds16(Ag + k0 + (size_t)16 * K, AsB + 16 * 32);
        gl_lds16(Wg + k0, BsB);
        gl_lds16(Wg + k0 + (size_t)16 * K, BsB + 16 * 32);
        __syncthreads();

        short8 a_f[4], b_f[4];
#pragma unroll
        for (int i = 0; i < 4; ++i)
            a_f[i] = *(const short8*)&As[(wr * 64 + i * 16 + l16) * 32 + quad * 8];
#pragma unroll
        for (int j = 0; j < 4; ++j)
            b_f[j] = *(const short8*)&Bs[(wc * 64 + j * 16 + l16) * 32 + quad * 8];
#pragma unroll
        for (int i = 0; i < 4; ++i)
#pragma unroll
            for (int j = 0; j < 4; ++j)
                acc[i][j] = __builtin_amdgcn_mfma_f32_16x16x32_bf16(a_f[i], b_f[j], acc[i][j], 0, 0, 0);
        __syncthreads();
    }

    float bj[4];
#pragma unroll
    for (int j = 0; j < 4; ++j)
        bj[j] = bias ? bias[n0 + wc * 64 + j * 16 + l16] : 0.0f;
#pragma unroll
    for (int i = 0; i < 4; ++i) {
#pragma unroll
        for (int r = 0; r < 4; ++r) {
            size_t row = m0 + wr * 64 + i * 16 + quad * 4 + r;
#pragma unroll
            for (int j = 0; j < 4; ++j) {
                size_t col = n0 + wc * 64 + j * 16 + l16;
                float val = acc[i][j][r] + bj[j];
                if (OUT_BF16)
                    ((unsigned short*)Cout)[row * N + col] = (unsigned short)f2bf1(val);
                else
                    ((float*)Cout)[row * N + col] = val;
            }
        }
    }
}

// ---------------------------------------------------------------------------
// RoPE on bf16 qkv buffer [M, 3072] (q cols 0..2047, k cols 2048..2559).
// Table-based: cos/sin from precomputed [2048][64] f32 tables (no device
// trig in hot path). One block per row, 256 threads x 5 pairs.
// ---------------------------------------------------------------------------
__global__ __launch_bounds__(256) void rope_kernel(
    unsigned short* __restrict__ qkv,
    const float* __restrict__ ctab, const float* __restrict__ stab)
{
    const int m = blockIdx.x;          // row in [0, B*S)
    const int s = m & (SS - 1);
    unsigned short* p = qkv + (size_t)m * 3072;
    const float* cr = ctab + s * 64;
    const float* sr = stab + s * 64;
#pragma unroll
    for (int it = 0; it < 5; ++it) {
        int idx = threadIdx.x + it * 256;   // 0..1279 : 20 heads x 64 pairs
        int hh = idx >> 6;
        int d  = idx & 63;
        int cb = (hh < 16) ? hh * 128 : 2048 + (hh - 16) * 128;
        float c  = cr[d];
        float sn = sr[d];
        union { unsigned int u; float f; } x1, x2;
        x1.u = ((unsigned int)p[cb + d]) << 16;
        x2.u = ((unsigned int)p[cb + d + 64]) << 16;
        p[cb + d]      = (unsigned short)f2bf1(x1.f * c - x2.f * sn);
        p[cb + d + 64] = (unsigned short)f2bf1(x2.f * c + x1.f * sn);
    }
}

// ---------------------------------------------------------------------------
// Flash attention, bf16, MFMA 16x16x32, XOR-swizzled LDS (conflict-free),
// double-buffered K/V with register prefetch -> ONE barrier per K-tile.
// 512 blocks, each does TWO q-tiles (jpair, 31-jpair) = uniform 33 KV-units.
// Structure lessons (rounds 1/2/4): (256,4) bound -> 64 VGPR + spill (358us);
// single-buffer 2-barrier loops -> 190us regardless of grid (occupancy is
// capped by register file, not LDS). Keep dbuf + (256,2). This round:
//   - XCD swizzle: linear bid -> swz=(bid&7)*64+(bid>>3): each XCD owns one
//     (b, kv-group) -> its 1MB K/V working set is L2-resident.
//   - T13 defer-rescale: skip Oacc rescale + m-update when the tile max is
//     within 64 (raw score) of running max (P bounded by 2^8.2, f32 l ok).
//   - s_setprio(1) around QK and PV MFMA clusters (m191: +4-7% on attn).
// qkv: [B*S, 3072] (q: h*128, k: 2048+kv*128, v: 2560+kv*128); o: [B*S, 2048].
// Swizzle keys: K/V chunk' = chunk ^ ((row + (row>>4)) & 7) at 16B-chunk
// granularity; P chunk' = chunk ^ ((row>>2) ^ ((row&3)<<1)).
// ---------------------------------------------------------------------------
__global__ __launch_bounds__(256, 2) void attn_mfma_kernel(
    const unsigned short* __restrict__ qkv, unsigned short* __restrict__ o)
{
    __shared__ unsigned int Ks_u[2][64 * 64];    // 2 x 16 KB
    __shared__ unsigned int Vs_u[2][128 * 32];   // 2 x 16 KB
    __shared__ unsigned short Ps[4][16 * 64];    // 8 KB, per-wave

    const int tid  = threadIdx.x;
    const int w    = tid >> 6;
    const int lane = tid & 63;
    const int quad = lane >> 4;
    const int l16  = lane & 15;

    // XCD-chunked remap of the 512-block grid (wg i -> XCD i%8):
    // swz in [xcd*64, xcd*64+64) covers one b and 4 consecutive h (one kv grp)
    const int bid   = (blockIdx.z * 16 + blockIdx.y) * 16 + blockIdx.x;
    const int swz   = (bid & 7) * 64 + (bid >> 3);
    const int jpair = swz & 15;     // 0..15
    const int h     = (swz >> 4) & 15;
    const int b     = swz >> 8;
    const int kv    = h >> 2;       // G = 4

    const float k2 = 0.12752789744920764f;  // (1/sqrt(128)) * log2(e)

    const unsigned short* kbase = qkv + (size_t)b * SS * 3072 + 2048 + kv * 128;
    const unsigned short* vbase = kbase + 512;

    const int kc  = tid & 15;          // K chunk (8 dims)
    const int kp0 = tid >> 4;          // K row base 0..15
    const int vpp = tid >> 3;          // V pos-pair 0..31
    const int vd0 = (tid & 7) * 16;    // V d-segment base

    for (int pass = 0; pass < 2; ++pass) {
        const int qt = pass ? (QTILES - 1 - jpair) : jpair;
        const int q0 = qt * 64;

        // ---- Q A-frags ----
        short8 qf[4];
        {
            const unsigned short* qp = qkv + (size_t)(b * SS + q0 + w * 16 + l16) * 3072 + h * 128 + quad * 8;
#pragma unroll
            for (int ks = 0; ks < 4; ++ks)
                qf[ks] = *(const short8*)(qp + ks * 32);
        }

        // ---- prefetch tile 0 into regs ----
        uint4 kpre[4], vpa[2], vpb[2];
        {
            const unsigned short* kg = kbase + (size_t)kp0 * 3072 + kc * 8;
#pragma unroll
            for (int rr = 0; rr < 4; ++rr)
                kpre[rr] = *(const uint4*)(kg + (size_t)rr * 16 * 3072);
            const unsigned short* vg = vbase + (size_t)(2 * vpp) * 3072 + vd0;
            vpa[0] = *(const uint4*)(vg);
            vpa[1] = *(const uint4*)(vg + 8);
            vpb[0] = *(const uint4*)(vg + 3072);
            vpb[1] = *(const uint4*)(vg + 3072 + 8);
        }

        float m_r[4], l_r[4];
        f32x4 Oacc[8];
#pragma unroll
        for (int r = 0; r < 4; ++r) { m_r[r] = -1e30f; l_r[r] = 0.0f; }
#pragma unroll
        for (int ot = 0; ot < 8; ++ot) Oacc[ot] = (f32x4){0.f, 0.f, 0.f, 0.f};

        for (int t = 0; t <= qt; ++t) {
            const int buf = t & 1;
            unsigned int* Kb = Ks_u[buf];
            unsigned int* Vb = Vs_u[buf];

            // ---- staged regs -> LDS (swizzled, conflict-free) ----
#pragma unroll
            for (int rr = 0; rr < 4; ++rr) {
                int pos = kp0 + rr * 16;
                int key = (kp0 + rr) & 7;           // (pos + (pos>>4)) & 7
                *(uint4*)&Kb[pos * 64 + (kc ^ key) * 4] = kpre[rr];
            }
            {
                const unsigned int* pa = (const unsigned int*)vpa;
                const unsigned int* pb = (const unsigned int*)vpb;
#pragma unroll
                for (int j = 0; j < 8; ++j) {
                    unsigned lo = __builtin_amdgcn_perm(pb[j], pa[j], 0x05040100);
                    unsigned hi = __builtin_amdgcn_perm(pb[j], pa[j], 0x07060302);
                    int d0 = vd0 + 2 * j;
                    int g  = d0 >> 4;               // same for d0 and d0+1
                    int k0 = (d0 + g) & 7;
                    int k1 = (d0 + 1 + g) & 7;
                    Vb[d0 * 32 + (((vpp >> 2) ^ k0) & 7) * 4 + (vpp & 3)] = lo;
                    Vb[(d0 + 1) * 32 + (((vpp >> 2) ^ k1) & 7) * 4 + (vpp & 3)] = hi;
                }
            }

            // ---- prefetch tile t+1 (latency hidden under compute) ----
            if (t < qt) {
                const unsigned short* kg = kbase + (size_t)((t + 1) * 64 + kp0) * 3072 + kc * 8;
#pragma unroll
                for (int rr = 0; rr < 4; ++rr)
                    kpre[rr] = *(const uint4*)(kg + (size_t)rr * 16 * 3072);
                const unsigned short* vg = vbase + (size_t)((t + 1) * 64 + 2 * vpp) * 3072 + vd0;
                vpa[0] = *(const uint4*)(vg);
                vpa[1] = *(const uint4*)(vg + 8);
                vpb[0] = *(const uint4*)(vg + 3072);
                vpb[1] = *(const uint4*)(vg + 3072 + 8);
            }
            __syncthreads();

            // ---- S = Q @ K^T (16x64 per wave), raw scores ----
            f32x4 S[4];
            __builtin_amdgcn_s_setprio(1);
#pragma unroll
            for (int ct = 0; ct < 4; ++ct) {
                f32x4 s = (f32x4){0.f, 0.f, 0.f, 0.f};
                const int row = ct * 16 + l16;
                const int key = (l16 + ct) & 7;     // (pos + (pos>>4)) & 7
#pragma unroll
                for (int ks = 0; ks < 4; ++ks) {
                    short8 kf = *(const short8*)&Kb[row * 64 + ((ks * 4 + quad) ^ key) * 4];
                    s = __builtin_amdgcn_mfma_f32_16x16x32_bf16(qf[ks], kf, s, 0, 0, 0);
                }
                S[ct] = s;
            }
            __builtin_amdgcn_s_setprio(0);

            // ---- causal mask (diagonal tile only) ----
            if (t == qt) {
                const int rowloc = w * 16 + quad * 4;
#pragma unroll
                for (int ct = 0; ct < 4; ++ct)
#pragma unroll
                    for (int r = 0; r < 4; ++r)
                        if (ct * 16 + l16 > rowloc + r) S[ct][r] = -1e30f;
            }

            // ---- online softmax (scale folded into exp2; T13 defer) ----
#pragma unroll
            for (int r = 0; r < 4; ++r) {
                float c0 = fmaxf(fmaxf(S[0][r], S[1][r]), fmaxf(S[2][r], S[3][r]));
                c0 = fmaxf(c0, __shfl_xor(c0, 1));
                c0 = fmaxf(c0, __shfl_xor(c0, 2));
                c0 = fmaxf(c0, __shfl_xor(c0, 4));
                c0 = fmaxf(c0, __shfl_xor(c0, 8));
                // defer-rescale: if tile max within 64 of running max for all
                // rows of this wave, keep old m (P bounded by 2^(64*k2)=2^8.2)
                if (!__all(c0 <= m_r[r] + 64.0f)) {
                    float mnew = fmaxf(m_r[r], c0);
                    float alpha = exp2f((m_r[r] - mnew) * k2);
                    m_r[r] = mnew;
                    l_r[r] *= alpha;
#pragma unroll
                    for (int ot = 0; ot < 8; ++ot) Oacc[ot][r] *= alpha;
                }
                float mh = m_r[r] * k2;
                float rs = 0.0f;
                const int prow = quad * 4 + r;
                const int pkey = (prow >> 2) ^ ((prow & 3) << 1);
#pragma unroll
                for (int ct = 0; ct < 4; ++ct) {
                    float p = exp2f(S[ct][r] * k2 - mh);
                    rs += p;
                    int chunk = ct * 2 + (l16 >> 3);
                    union { float f; unsigned u; } pu; pu.f = p;
                    Ps[w][prow * 64 + (chunk ^ pkey) * 8 + (l16 & 7)] =
                        (unsigned short)((pu.u + 0x8000u) >> 16);
                }
                rs += __shfl_xor(rs, 1);
                rs += __shfl_xor(rs, 2);
                rs += __shfl_xor(rs, 4);
                rs += __shfl_xor(rs, 8);
                l_r[r] += rs;
            }

            // ---- O += P @ V ----
            {
                const int pkeyr = (l16 >> 2) ^ ((l16 & 3) << 1);
                short8 pf0 = *(const short8*)&Ps[w][l16 * 64 + (quad ^ pkeyr) * 8];
                short8 pf1 = *(const short8*)&Ps[w][l16 * 64 + ((4 + quad) ^ pkeyr) * 8];
                __builtin_amdgcn_s_setprio(1);
#pragma unroll
                for (int ot = 0; ot < 8; ++ot) {
                    const int d = ot * 16 + l16;
                    const int vkey = (l16 + ot) & 7;    // (d + (d>>4)) & 7
                    short8 v0 = *(const short8*)&Vb[d * 32 + (quad ^ vkey) * 4];
                    Oacc[ot] = __builtin_amdgcn_mfma_f32_16x16x32_bf16(pf0, v0, Oacc[ot], 0, 0, 0);
                    short8 v1 = *(const short8*)&Vb[d * 32 + ((4 + quad) ^ vkey) * 4];
                    Oacc[ot] = __builtin_amdgcn_mfma_f32_16x16x32_bf16(pf1, v1, Oacc[ot], 0, 0, 0);
                }
                __builtin_amdgcn_s_setprio(0);
            }
            // no tail barrier: next iteration writes the other buffer
        }

        // ---- epilogue: bf16 store to [B*S, 2048] ----
        float inv[4];
#pragma unroll
        for (int r = 0; r < 4; ++r) inv[r] = 1.0f / l_r[r];
        const int orow0 = q0 + w * 16 + quad * 4;
        unsigned short* ob = o + (size_t)(b * SS + orow0) * 2048 + h * 128 + l16;
#pragma unroll
        for (int r = 0; r < 4; ++r)
#pragma unroll
            for (int ot = 0; ot < 8; ++ot)
                ob[(size_t)r * 2048 + ot * 16] = (unsigned short)f2bf1(Oacc[ot][r] * inv[r]);

        __syncthreads();   // protect LDS buffers across pass boundary
    }
}

// ---------------------------------------------------------------------------
extern "C" void kernel_launch(void* const* d_in, const int* in_sizes, int n_in,
                              void* d_out, int out_size, void* d_ws, size_t ws_size,
                              hipStream_t stream)
{
    const float* x  = (const float*)d_in[0];
    const float* Wq = (const float*)d_in[1];
    const float* bq = (const float*)d_in[2];
    const float* Wk = (const float*)d_in[3];
    const float* bk = (const float*)d_in[4];
    const float* Wv = (const float*)d_in[5];
    const float* bv = (const float*)d_in[6];
    const float* Wo = (const float*)d_in[7];
    float* out = (float*)d_out;

    const int M = BB * SS;  // 4096
    char* wsb = (char*)d_ws;
    unsigned short* xb   = (unsigned short*)wsb;  wsb += (size_t)M * EE * 2;        // 16.8 MB
    unsigned short* wqkv = (unsigned short*)wsb;  wsb += (size_t)3072 * EE * 2;     // 12.6 MB
    unsigned short* wob  = (unsigned short*)wsb;  wsb += (size_t)EE * EE * 2;       //  8.4 MB
    unsigned short* qkvb = (unsigned short*)wsb;  wsb += (size_t)M * 3072 * 2;      // 25.2 MB
    unsigned short* abb  = (unsigned short*)wsb;  wsb += (size_t)M * 2048 * 2;      // 16.8 MB
    float* bqkv = (float*)wsb;                    wsb += 4096 * 4;                  // 16 KB (2560 used)
    float* rtab = (float*)wsb;                    // 1 MB: cos[2048*64] | sin[2048*64]

    // one fused conversion launch (x, Wq, Wk, Wv, Wo, biases, rope table)
    cvt_all_kernel<<<18947, 256, 0, stream>>>(x, Wq, Wk, Wv, Wo, bq, bk, bv,
                                              xb, wqkv, wob, bqkv, rtab);

    // fused QKV projection: [M,3072] = xb @ wqkv^T + bqkv (bf16 out)
    gemm_mfma_kernel<true><<<dim3(3072 / 128, M / 128), 256, 0, stream>>>(
        xb, wqkv, bqkv, qkvb, M, 3072, EE);

    // RoPE on q and k heads, table-based, one block per row
    rope_kernel<<<M, 256, 0, stream>>>(qkvb, rtab, rtab + 131072);

    // flash attention -> abb (bf16)
    attn_mfma_kernel<<<dim3(16, HH, BB), 256, 0, stream>>>(qkvb, abb);

    // output projection: out = abb @ wob^T (fp32 out)
    gemm_mfma_kernel<false><<<dim3(EE / 128, M / 128), 256, 0, stream>>>(
        abb, wob, nullptr, out, M, EE, 2048);
}

// Round 7
// 388.480 us; speedup vs baseline: 1.1044x; 1.0260x over previous
//
#include <hip/hip_runtime.h>
#include <hip/hip_bf16.h>
#include <math.h>

// Problem constants (QwenAttention: B=2,S=2048,E=2048,H=16,KV=4,D=128)
#define BB 2
#define SS 2048
#define EE 2048
#define HH 16
#define KVH 4
#define DD 128
#define QTILES 32   // S / 64

typedef short short8 __attribute__((ext_vector_type(8)));
typedef float f32x4 __attribute__((ext_vector_type(4)));

__device__ __forceinline__ unsigned int f2bf1(float x) {
    union { float f; unsigned int u; } v; v.f = x;
    return (v.u + 0x7FFFu + ((v.u >> 16) & 1u)) >> 16;  // RNE bf16
}
__device__ __forceinline__ unsigned int packbf(float a, float b) {
    return f2bf1(a) | (f2bf1(b) << 16);
}
// async global->LDS, 16B per lane; LDS dest = wave-uniform base + lane*16
__device__ __forceinline__ void gl_lds16(const void* g, void* l) {
    __builtin_amdgcn_global_load_lds(
        (const __attribute__((address_space(1))) unsigned int*)g,
        (__attribute__((address_space(3))) unsigned int*)l,
        16, 0, 0);
}

// ---------------------------------------------------------------------------
// Fused fp32->bf16 conversion of all inputs + bias concat + RoPE cos/sin
// table, one launch. Segments in float4 units: x | Wq | Wk | Wv | Wo |
// biases(fp32) | rope table (cos[2048][64], sin[2048][64] f32).
// ---------------------------------------------------------------------------
__global__ __launch_bounds__(256) void cvt_all_kernel(
    const float* __restrict__ x,  const float* __restrict__ Wq,
    const float* __restrict__ Wk, const float* __restrict__ Wv,
    const float* __restrict__ Wo, const float* __restrict__ bq,
    const float* __restrict__ bk, const float* __restrict__ bv,
    unsigned short* __restrict__ xb, unsigned short* __restrict__ wqkv,
    unsigned short* __restrict__ wob, float* __restrict__ bqkv,
    float* __restrict__ rtab)
{
    long id = (long)blockIdx.x * 256 + threadIdx.x;
    const float* src; unsigned short* dst; long j;
    if (id < 2097152)      { j = id;           src = x;  dst = xb; }
    else if (id < 3145728) { j = id - 2097152; src = Wq; dst = wqkv; }
    else if (id < 3407872) { j = id - 3145728; src = Wk; dst = wqkv + 4194304; }
    else if (id < 3670016) { j = id - 3407872; src = Wv; dst = wqkv + 5242880; }
    else if (id < 4718592) { j = id - 3670016; src = Wo; dst = wob; }
    else if (id < 4719360) {
        long c = (id - 4718592) * 4;
#pragma unroll
        for (int e = 0; e < 4; ++e) {
            long cc = c + e;
            bqkv[cc] = (cc < 2048) ? bq[cc] : (cc < 2560 ? bk[cc - 2048] : bv[cc - 2560]);
        }
        return;
    } else if (id < 4850432) {
        // rope table: one sincos per (s, d) entry
        long e = id - 4719360;            // 0 .. 131071
        int sg = (int)(e >> 6);           // position 0..2047
        int dg = (int)(e & 63);           // freq index 0..63
        float inv_freq = expf(-(float)dg * (logf(10000.0f) / 64.0f));
        float fr = (float)sg * inv_freq;
        rtab[e]          = cosf(fr);
        rtab[131072 + e] = sinf(fr);
        return;
    } else return;
    float4 f = ((const float4*)src)[j];
    ((uint2*)dst)[j] = make_uint2(packbf(f.x, f.y), packbf(f.z, f.w));
}

// ---------------------------------------------------------------------------
// m97-style bf16 MFMA GEMM: C[M,N] = A[M,K] @ W[N,K]^T + bias[N]
// 128x128 tile, BK=32, 256 threads = 4 waves (2x2), 4x4 MFMA tiles per wave.
// DO_ROPE: fuse RoPE into the epilogue. Wave->column map is PERMUTED
// (col = wc*32 + (j&1)*16 + (j>>1)*64 + l16, a bijection of the 128 tile
// cols) so the rope pair (d, d+64) lives in acc[i][jp] / acc[i][jp+2] of
// the SAME thread -> no LDS/shuffle exchange needed. Rope applies to
// blocks with n0 < 2560 (q heads 0..2047, k heads 2048..2559); cos/sin
// from the precomputed [2048][64] f32 tables (L2-resident, 1 MB).
// This removes the standalone rope kernel (dispatch + 70 MB round-trip).
// ---------------------------------------------------------------------------
template <bool OUT_BF16, bool DO_ROPE>
__global__ __launch_bounds__(256) void gemm_mfma_kernel(
    const unsigned short* __restrict__ A, const unsigned short* __restrict__ W,
    const float* __restrict__ bias, void* __restrict__ Cout,
    int M, int N, int K,
    const float* __restrict__ ctab, const float* __restrict__ stab)
{
    __shared__ unsigned short As[128 * 32];
    __shared__ unsigned short Bs[128 * 32];

    const int tid  = threadIdx.x;
    const int w    = tid >> 6;
    const int lane = tid & 63;
    const int quad = lane >> 4;
    const int l16  = lane & 15;
    const int wr   = w >> 1, wc = w & 1;
    const int m0 = blockIdx.y * 128, n0 = blockIdx.x * 128;

    f32x4 acc[4][4];
#pragma unroll
    for (int i = 0; i < 4; ++i)
#pragma unroll
        for (int j = 0; j < 4; ++j) acc[i][j] = (f32x4){0.f, 0.f, 0.f, 0.f};

    const unsigned short* Ag = A + (size_t)(m0 + w * 32 + (lane >> 2)) * K + (lane & 3) * 8;
    const unsigned short* Wg = W + (size_t)(n0 + w * 32 + (lane >> 2)) * K + (lane & 3) * 8;
    unsigned short* AsB = &As[(w * 32) * 32];
    unsigned short* BsB = &Bs[(w * 32) * 32];

    for (int k0 = 0; k0 < K; k0 += 32) {
        gl_lds16(Ag + k0, AsB);
        gl_lds16(Ag + k0 + (size_t)16 * K, AsB + 16 * 32);
        gl_lds16(Wg + k0, BsB);
        gl_lds16(Wg + k0 + (size_t)16 * K, BsB + 16 * 32);
        __syncthreads();

        short8 a_f[4], b_f[4];
#pragma unroll
        for (int i = 0; i < 4; ++i)
            a_f[i] = *(const short8*)&As[(wr * 64 + i * 16 + l16) * 32 + quad * 8];
#pragma unroll
        for (int j = 0; j < 4; ++j)
            b_f[j] = *(const short8*)&Bs[(wc * 32 + (j & 1) * 16 + (j >> 1) * 64 + l16) * 32 + quad * 8];
#pragma unroll
        for (int i = 0; i < 4; ++i)
#pragma unroll
            for (int j = 0; j < 4; ++j)
                acc[i][j] = __builtin_amdgcn_mfma_f32_16x16x32_bf16(a_f[i], b_f[j], acc[i][j], 0, 0, 0);
        __syncthreads();
    }

    float bj[4];
#pragma unroll
    for (int j = 0; j < 4; ++j)
        bj[j] = bias ? bias[n0 + wc * 32 + (j & 1) * 16 + (j >> 1) * 64 + l16] : 0.0f;

    if (DO_ROPE && n0 < 2560) {
        // rope pair (dloc, dloc+64) in-thread: acc[i][jp] (low) / acc[i][jp+2] (high)
#pragma unroll
        for (int i = 0; i < 4; ++i) {
#pragma unroll
            for (int r = 0; r < 4; ++r) {
                size_t row = m0 + wr * 64 + i * 16 + quad * 4 + r;
                int s = (int)row & (SS - 1);
#pragma unroll
                for (int jp = 0; jp < 2; ++jp) {
                    int dloc = wc * 32 + jp * 16 + l16;      // 0..63
                    float c  = ctab[s * 64 + dloc];
                    float sn = stab[s * 64 + dloc];
                    float lo = acc[i][jp][r]     + bj[jp];
                    float hi = acc[i][jp + 2][r] + bj[jp + 2];
                    size_t col = (size_t)n0 + dloc;
                    ((unsigned short*)Cout)[row * N + col]      = (unsigned short)f2bf1(lo * c - hi * sn);
                    ((unsigned short*)Cout)[row * N + col + 64] = (unsigned short)f2bf1(hi * c + lo * sn);
                }
            }
        }
    } else {
#pragma unroll
        for (int i = 0; i < 4; ++i) {
#pragma unroll
            for (int r = 0; r < 4; ++r) {
                size_t row = m0 + wr * 64 + i * 16 + quad * 4 + r;
#pragma unroll
                for (int j = 0; j < 4; ++j) {
                    size_t col = n0 + wc * 32 + (j & 1) * 16 + (j >> 1) * 64 + l16;
                    float val = acc[i][j][r] + bj[j];
                    if (OUT_BF16)
                        ((unsigned short*)Cout)[row * N + col] = (unsigned short)f2bf1(val);
                    else
                        ((float*)Cout)[row * N + col] = val;
                }
            }
        }
    }
}

// ---------------------------------------------------------------------------
// Flash attention, bf16, MFMA 16x16x32, XOR-swizzled LDS (conflict-free),
// double-buffered K/V with register prefetch -> ONE barrier per K-tile.
// 512 blocks, each does TWO q-tiles (jpair, 31-jpair) = uniform 33 KV-units
// per block (the unique uniform static partition; measured 133-141 us).
// Lessons from rounds 1/2/4/6 (all regressed, keep THIS structure):
//   (256,4) bound -> 64 VGPR + spill (358us); single-buffer 2-barrier loops
//   -> 190us regardless of grid; split-KV -> 190us; XCD-swizzle+T13+setprio
//   bundle -> 164us (FETCH 67->22MB proved L2 locality, but kernel is
//   latency-bound at 7.5% HBM so it bought no time; setprio hurts the
//   barrier-synced lockstep waves, VGPR 112->128).
// qkv: [B*S, 3072] (q: h*128, k: 2048+kv*128, v: 2560+kv*128); o: [B*S, 2048].
// Swizzle keys: K/V chunk' = chunk ^ ((row + (row>>4)) & 7) at 16B-chunk
// granularity; P chunk' = chunk ^ ((row>>2) ^ ((row&3)<<1)).
// ---------------------------------------------------------------------------
__global__ __launch_bounds__(256, 2) void attn_mfma_kernel(
    const unsigned short* __restrict__ qkv, unsigned short* __restrict__ o)
{
    __shared__ unsigned int Ks_u[2][64 * 64];    // 2 x 16 KB
    __shared__ unsigned int Vs_u[2][128 * 32];   // 2 x 16 KB
    __shared__ unsigned short Ps[4][16 * 64];    // 8 KB, per-wave

    const int tid  = threadIdx.x;
    const int w    = tid >> 6;
    const int lane = tid & 63;
    const int quad = lane >> 4;
    const int l16  = lane & 15;
    const int jpair = blockIdx.x;   // 0..15
    const int h     = blockIdx.y;
    const int b     = blockIdx.z;
    const int kv    = h >> 2;       // G = 4

    const float k2 = 0.12752789744920764f;  // (1/sqrt(128)) * log2(e)

    const unsigned short* kbase = qkv + (size_t)b * SS * 3072 + 2048 + kv * 128;
    const unsigned short* vbase = kbase + 512;

    const int kc  = tid & 15;          // K chunk (8 dims)
    const int kp0 = tid >> 4;          // K row base 0..15
    const int vpp = tid >> 3;          // V pos-pair 0..31
    const int vd0 = (tid & 7) * 16;    // V d-segment base

    for (int pass = 0; pass < 2; ++pass) {
        const int qt = pass ? (QTILES - 1 - jpair) : jpair;
        const int q0 = qt * 64;

        // ---- Q A-frags ----
        short8 qf[4];
        {
            const unsigned short* qp = qkv + (size_t)(b * SS + q0 + w * 16 + l16) * 3072 + h * 128 + quad * 8;
#pragma unroll
            for (int ks = 0; ks < 4; ++ks)
                qf[ks] = *(const short8*)(qp + ks * 32);
        }

        // ---- prefetch tile 0 into regs ----
        uint4 kpre[4], vpa[2], vpb[2];
        {
            const unsigned short* kg = kbase + (size_t)kp0 * 3072 + kc * 8;
#pragma unroll
            for (int rr = 0; rr < 4; ++rr)
                kpre[rr] = *(const uint4*)(kg + (size_t)rr * 16 * 3072);
            const unsigned short* vg = vbase + (size_t)(2 * vpp) * 3072 + vd0;
            vpa[0] = *(const uint4*)(vg);
            vpa[1] = *(const uint4*)(vg + 8);
            vpb[0] = *(const uint4*)(vg + 3072);
            vpb[1] = *(const uint4*)(vg + 3072 + 8);
        }

        float m_r[4], l_r[4];
        f32x4 Oacc[8];
#pragma unroll
        for (int r = 0; r < 4; ++r) { m_r[r] = -1e30f; l_r[r] = 0.0f; }
#pragma unroll
        for (int ot = 0; ot < 8; ++ot) Oacc[ot] = (f32x4){0.f, 0.f, 0.f, 0.f};

        for (int t = 0; t <= qt; ++t) {
            const int buf = t & 1;
            unsigned int* Kb = Ks_u[buf];
            unsigned int* Vb = Vs_u[buf];

            // ---- staged regs -> LDS (swizzled, conflict-free) ----
#pragma unroll
            for (int rr = 0; rr < 4; ++rr) {
                int pos = kp0 + rr * 16;
                int key = (kp0 + rr) & 7;           // (pos + (pos>>4)) & 7
                *(uint4*)&Kb[pos * 64 + (kc ^ key) * 4] = kpre[rr];
            }
            {
                const unsigned int* pa = (const unsigned int*)vpa;
                const unsigned int* pb = (const unsigned int*)vpb;
#pragma unroll
                for (int j = 0; j < 8; ++j) {
                    unsigned lo = __builtin_amdgcn_perm(pb[j], pa[j], 0x05040100);
                    unsigned hi = __builtin_amdgcn_perm(pb[j], pa[j], 0x07060302);
                    int d0 = vd0 + 2 * j;
                    int g  = d0 >> 4;               // same for d0 and d0+1
                    int k0 = (d0 + g) & 7;
                    int k1 = (d0 + 1 + g) & 7;
                    Vb[d0 * 32 + (((vpp >> 2) ^ k0) & 7) * 4 + (vpp & 3)] = lo;
                    Vb[(d0 + 1) * 32 + (((vpp >> 2) ^ k1) & 7) * 4 + (vpp & 3)] = hi;
                }
            }

            // ---- prefetch tile t+1 (latency hidden under compute) ----
            if (t < qt) {
                const unsigned short* kg = kbase + (size_t)((t + 1) * 64 + kp0) * 3072 + kc * 8;
#pragma unroll
                for (int rr = 0; rr < 4; ++rr)
                    kpre[rr] = *(const uint4*)(kg + (size_t)rr * 16 * 3072);
                const unsigned short* vg = vbase + (size_t)((t + 1) * 64 + 2 * vpp) * 3072 + vd0;
                vpa[0] = *(const uint4*)(vg);
                vpa[1] = *(const uint4*)(vg + 8);
                vpb[0] = *(const uint4*)(vg + 3072);
                vpb[1] = *(const uint4*)(vg + 3072 + 8);
            }
            __syncthreads();

            // ---- S = Q @ K^T (16x64 per wave), raw scores ----
            f32x4 S[4];
#pragma unroll
            for (int ct = 0; ct < 4; ++ct) {
                f32x4 s = (f32x4){0.f, 0.f, 0.f, 0.f};
                const int row = ct * 16 + l16;
                const int key = (l16 + ct) & 7;     // (pos + (pos>>4)) & 7
#pragma unroll
                for (int ks = 0; ks < 4; ++ks) {
                    short8 kf = *(const short8*)&Kb[row * 64 + ((ks * 4 + quad) ^ key) * 4];
                    s = __builtin_amdgcn_mfma_f32_16x16x32_bf16(qf[ks], kf, s, 0, 0, 0);
                }
                S[ct] = s;
            }

            // ---- causal mask (diagonal tile only) ----
            if (t == qt) {
                const int rowloc = w * 16 + quad * 4;
#pragma unroll
                for (int ct = 0; ct < 4; ++ct)
#pragma unroll
                    for (int r = 0; r < 4; ++r)
                        if (ct * 16 + l16 > rowloc + r) S[ct][r] = -1e30f;
            }

            // ---- online softmax (scale folded into exp2) ----
#pragma unroll
            for (int r = 0; r < 4; ++r) {
                float c0 = fmaxf(fmaxf(S[0][r], S[1][r]), fmaxf(S[2][r], S[3][r]));
                c0 = fmaxf(c0, __shfl_xor(c0, 1));
                c0 = fmaxf(c0, __shfl_xor(c0, 2));
                c0 = fmaxf(c0, __shfl_xor(c0, 4));
                c0 = fmaxf(c0, __shfl_xor(c0, 8));
                float mnew = fmaxf(m_r[r], c0);
                float alpha = exp2f((m_r[r] - mnew) * k2);
                m_r[r] = mnew;
                float mh = mnew * k2;
                float rs = 0.0f;
                const int prow = quad * 4 + r;
                const int pkey = (prow >> 2) ^ ((prow & 3) << 1);
#pragma unroll
                for (int ct = 0; ct < 4; ++ct) {
                    float p = exp2f(S[ct][r] * k2 - mh);
                    rs += p;
                    int chunk = ct * 2 + (l16 >> 3);
                    union { float f; unsigned u; } pu; pu.f = p;
                    Ps[w][prow * 64 + (chunk ^ pkey) * 8 + (l16 & 7)] =
                        (unsigned short)((pu.u + 0x8000u) >> 16);
                }
                rs += __shfl_xor(rs, 1);
                rs += __shfl_xor(rs, 2);
                rs += __shfl_xor(rs, 4);
                rs += __shfl_xor(rs, 8);
                l_r[r] = l_r[r] * alpha + rs;
#pragma unroll
                for (int ot = 0; ot < 8; ++ot) Oacc[ot][r] *= alpha;
            }

            // ---- O += P @ V ----
            {
                const int pkeyr = (l16 >> 2) ^ ((l16 & 3) << 1);
                short8 pf0 = *(const short8*)&Ps[w][l16 * 64 + (quad ^ pkeyr) * 8];
                short8 pf1 = *(const short8*)&Ps[w][l16 * 64 + ((4 + quad) ^ pkeyr) * 8];
#pragma unroll
                for (int ot = 0; ot < 8; ++ot) {
                    const int d = ot * 16 + l16;
                    const int vkey = (l16 + ot) & 7;    // (d + (d>>4)) & 7
                    short8 v0 = *(const short8*)&Vb[d * 32 + (quad ^ vkey) * 4];
                    Oacc[ot] = __builtin_amdgcn_mfma_f32_16x16x32_bf16(pf0, v0, Oacc[ot], 0, 0, 0);
                    short8 v1 = *(const short8*)&Vb[d * 32 + ((4 + quad) ^ vkey) * 4];
                    Oacc[ot] = __builtin_amdgcn_mfma_f32_16x16x32_bf16(pf1, v1, Oacc[ot], 0, 0, 0);
                }
            }
            // no tail barrier: next iteration writes the other buffer
        }

        // ---- epilogue: bf16 store to [B*S, 2048] ----
        float inv[4];
#pragma unroll
        for (int r = 0; r < 4; ++r) inv[r] = 1.0f / l_r[r];
        const int orow0 = q0 + w * 16 + quad * 4;
        unsigned short* ob = o + (size_t)(b * SS + orow0) * 2048 + h * 128 + l16;
#pragma unroll
        for (int r = 0; r < 4; ++r)
#pragma unroll
            for (int ot = 0; ot < 8; ++ot)
                ob[(size_t)r * 2048 + ot * 16] = (unsigned short)f2bf1(Oacc[ot][r] * inv[r]);

        __syncthreads();   // protect LDS buffers across pass boundary
    }
}

// ---------------------------------------------------------------------------
extern "C" void kernel_launch(void* const* d_in, const int* in_sizes, int n_in,
                              void* d_out, int out_size, void* d_ws, size_t ws_size,
                              hipStream_t stream)
{
    const float* x  = (const float*)d_in[0];
    const float* Wq = (const float*)d_in[1];
    const float* bq = (const float*)d_in[2];
    const float* Wk = (const float*)d_in[3];
    const float* bk = (const float*)d_in[4];
    const float* Wv = (const float*)d_in[5];
    const float* bv = (const float*)d_in[6];
    const float* Wo = (const float*)d_in[7];
    float* out = (float*)d_out;

    const int M = BB * SS;  // 4096
    char* wsb = (char*)d_ws;
    unsigned short* xb   = (unsigned short*)wsb;  wsb += (size_t)M * EE * 2;        // 16.8 MB
    unsigned short* wqkv = (unsigned short*)wsb;  wsb += (size_t)3072 * EE * 2;     // 12.6 MB
    unsigned short* wob  = (unsigned short*)wsb;  wsb += (size_t)EE * EE * 2;       //  8.4 MB
    unsigned short* qkvb = (unsigned short*)wsb;  wsb += (size_t)M * 3072 * 2;      // 25.2 MB
    unsigned short* abb  = (unsigned short*)wsb;  wsb += (size_t)M * 2048 * 2;      // 16.8 MB
    float* bqkv = (float*)wsb;                    wsb += 4096 * 4;                  // 16 KB (2560 used)
    float* rtab = (float*)wsb;                    // 1 MB: cos[2048*64] | sin[2048*64]

    // one fused conversion launch (x, Wq, Wk, Wv, Wo, biases, rope table)
    cvt_all_kernel<<<18947, 256, 0, stream>>>(x, Wq, Wk, Wv, Wo, bq, bk, bv,
                                              xb, wqkv, wob, bqkv, rtab);

    // fused QKV projection + RoPE epilogue: [M,3072] = xb @ wqkv^T + bqkv,
    // rope applied in-register to q/k head columns (bf16 out)
    gemm_mfma_kernel<true, true><<<dim3(3072 / 128, M / 128), 256, 0, stream>>>(
        xb, wqkv, bqkv, qkvb, M, 3072, EE, rtab, rtab + 131072);

    // flash attention -> abb (bf16)
    attn_mfma_kernel<<<dim3(16, HH, BB), 256, 0, stream>>>(qkvb, abb);

    // output projection: out = abb @ wob^T (fp32 out)
    gemm_mfma_kernel<false, false><<<dim3(EE / 128, M / 128), 256, 0, stream>>>(
        abb, wob, nullptr, out, M, EE, 2048, nullptr, nullptr);
}

// Round 8
// 359.952 us; speedup vs baseline: 1.1919x; 1.0793x over previous
//
#include <hip/hip_runtime.h>
#include <hip/hip_bf16.h>
#include <math.h>

// Problem constants (QwenAttention: B=2,S=2048,E=2048,H=16,KV=4,D=128)
#define BB 2
#define SS 2048
#define EE 2048
#define HH 16
#define KVH 4
#define DD 128
#define QTILES 32   // S / 64

typedef short short8 __attribute__((ext_vector_type(8)));
typedef float f32x4 __attribute__((ext_vector_type(4)));

__device__ __forceinline__ unsigned int f2bf1(float x) {
    union { float f; unsigned int u; } v; v.f = x;
    return (v.u + 0x7FFFu + ((v.u >> 16) & 1u)) >> 16;  // RNE bf16
}
__device__ __forceinline__ unsigned int packbf(float a, float b) {
    return f2bf1(a) | (f2bf1(b) << 16);
}
// async global->LDS, 16B per lane; LDS dest = wave-uniform base + lane*16
__device__ __forceinline__ void gl_lds16(const void* g, void* l) {
    __builtin_amdgcn_global_load_lds(
        (const __attribute__((address_space(1))) unsigned int*)g,
        (__attribute__((address_space(3))) unsigned int*)l,
        16, 0, 0);
}

// ---------------------------------------------------------------------------
// Fused fp32->bf16 conversion of all inputs + bias concat + RoPE cos/sin
// table, one launch. Segments in float4 units: x | Wq | Wk | Wv | Wo |
// biases(fp32) | rope table (cos[2048][64], sin[2048][64] f32).
// ---------------------------------------------------------------------------
__global__ __launch_bounds__(256) void cvt_all_kernel(
    const float* __restrict__ x,  const float* __restrict__ Wq,
    const float* __restrict__ Wk, const float* __restrict__ Wv,
    const float* __restrict__ Wo, const float* __restrict__ bq,
    const float* __restrict__ bk, const float* __restrict__ bv,
    unsigned short* __restrict__ xb, unsigned short* __restrict__ wqkv,
    unsigned short* __restrict__ wob, float* __restrict__ bqkv,
    float* __restrict__ rtab)
{
    long id = (long)blockIdx.x * 256 + threadIdx.x;
    const float* src; unsigned short* dst; long j;
    if (id < 2097152)      { j = id;           src = x;  dst = xb; }
    else if (id < 3145728) { j = id - 2097152; src = Wq; dst = wqkv; }
    else if (id < 3407872) { j = id - 3145728; src = Wk; dst = wqkv + 4194304; }
    else if (id < 3670016) { j = id - 3407872; src = Wv; dst = wqkv + 5242880; }
    else if (id < 4718592) { j = id - 3670016; src = Wo; dst = wob; }
    else if (id < 4719360) {
        long c = (id - 4718592) * 4;
#pragma unroll
        for (int e = 0; e < 4; ++e) {
            long cc = c + e;
            bqkv[cc] = (cc < 2048) ? bq[cc] : (cc < 2560 ? bk[cc - 2048] : bv[cc - 2560]);
        }
        return;
    } else if (id < 4850432) {
        // rope table: one sincos per (s, d) entry
        long e = id - 4719360;            // 0 .. 131071
        int sg = (int)(e >> 6);           // position 0..2047
        int dg = (int)(e & 63);           // freq index 0..63
        float inv_freq = expf(-(float)dg * (logf(10000.0f) / 64.0f));
        float fr = (float)sg * inv_freq;
        rtab[e]          = cosf(fr);
        rtab[131072 + e] = sinf(fr);
        return;
    } else return;
    float4 f = ((const float4*)src)[j];
    ((uint2*)dst)[j] = make_uint2(packbf(f.x, f.y), packbf(f.z, f.w));
}

// ---------------------------------------------------------------------------
// m97-style bf16 MFMA GEMM: C[M,N] = A[M,K] @ W[N,K]^T + bias[N]
// 128x128 tile, BK=32, 256 threads = 4 waves (2x2), 4x4 MFMA tiles per wave.
// (r7 lesson: rope-fused epilogue with permuted column map cost ~34 us vs
//  the ~7 us standalone rope kernel it replaced -- keep epilogue simple.)
// ---------------------------------------------------------------------------
template <bool OUT_BF16>
__global__ __launch_bounds__(256) void gemm_mfma_kernel(
    const unsigned short* __restrict__ A, const unsigned short* __restrict__ W,
    const float* __restrict__ bias, void* __restrict__ Cout,
    int M, int N, int K)
{
    __shared__ unsigned short As[128 * 32];
    __shared__ unsigned short Bs[128 * 32];

    const int tid  = threadIdx.x;
    const int w    = tid >> 6;
    const int lane = tid & 63;
    const int quad = lane >> 4;
    const int l16  = lane & 15;
    const int wr   = w >> 1, wc = w & 1;
    const int m0 = blockIdx.y * 128, n0 = blockIdx.x * 128;

    f32x4 acc[4][4];
#pragma unroll
    for (int i = 0; i < 4; ++i)
#pragma unroll
        for (int j = 0; j < 4; ++j) acc[i][j] = (f32x4){0.f, 0.f, 0.f, 0.f};

    const unsigned short* Ag = A + (size_t)(m0 + w * 32 + (lane >> 2)) * K + (lane & 3) * 8;
    const unsigned short* Wg = W + (size_t)(n0 + w * 32 + (lane >> 2)) * K + (lane & 3) * 8;
    unsigned short* AsB = &As[(w * 32) * 32];
    unsigned short* BsB = &Bs[(w * 32) * 32];

    for (int k0 = 0; k0 < K; k0 += 32) {
        gl_lds16(Ag + k0, AsB);
        gl_lds16(Ag + k0 + (size_t)16 * K, AsB + 16 * 32);
        gl_lds16(Wg + k0, BsB);
        gl_lds16(Wg + k0 + (size_t)16 * K, BsB + 16 * 32);
        __syncthreads();

        short8 a_f[4], b_f[4];
#pragma unroll
        for (int i = 0; i < 4; ++i)
            a_f[i] = *(const short8*)&As[(wr * 64 + i * 16 + l16) * 32 + quad * 8];
#pragma unroll
        for (int j = 0; j < 4; ++j)
            b_f[j] = *(const short8*)&Bs[(wc * 64 + j * 16 + l16) * 32 + quad * 8];
#pragma unroll
        for (int i = 0; i < 4; ++i)
#pragma unroll
            for (int j = 0; j < 4; ++j)
                acc[i][j] = __builtin_amdgcn_mfma_f32_16x16x32_bf16(a_f[i], b_f[j], acc[i][j], 0, 0, 0);
        __syncthreads();
    }

    float bj[4];
#pragma unroll
    for (int j = 0; j < 4; ++j)
        bj[j] = bias ? bias[n0 + wc * 64 + j * 16 + l16] : 0.0f;
#pragma unroll
    for (int i = 0; i < 4; ++i) {
#pragma unroll
        for (int r = 0; r < 4; ++r) {
            size_t row = m0 + wr * 64 + i * 16 + quad * 4 + r;
#pragma unroll
            for (int j = 0; j < 4; ++j) {
                size_t col = n0 + wc * 64 + j * 16 + l16;
                float val = acc[i][j][r] + bj[j];
                if (OUT_BF16)
                    ((unsigned short*)Cout)[row * N + col] = (unsigned short)f2bf1(val);
                else
                    ((float*)Cout)[row * N + col] = val;
            }
        }
    }
}

// ---------------------------------------------------------------------------
// RoPE on bf16 qkv buffer [M, 3072] (q cols 0..2047, k cols 2048..2559).
// Table-based: cos/sin from precomputed [2048][64] f32 tables (no device
// trig in hot path). One block per row, 256 threads x 5 pairs.
// ---------------------------------------------------------------------------
__global__ __launch_bounds__(256) void rope_kernel(
    unsigned short* __restrict__ qkv,
    const float* __restrict__ ctab, const float* __restrict__ stab)
{
    const int m = blockIdx.x;          // row in [0, B*S)
    const int s = m & (SS - 1);
    unsigned short* p = qkv + (size_t)m * 3072;
    const float* cr = ctab + s * 64;
    const float* sr = stab + s * 64;
#pragma unroll
    for (int it = 0; it < 5; ++it) {
        int idx = threadIdx.x + it * 256;   // 0..1279 : 20 heads x 64 pairs
        int hh = idx >> 6;
        int d  = idx & 63;
        int cb = (hh < 16) ? hh * 128 : 2048 + (hh - 16) * 128;
        float c  = cr[d];
        float sn = sr[d];
        union { unsigned int u; float f; } x1, x2;
        x1.u = ((unsigned int)p[cb + d]) << 16;
        x2.u = ((unsigned int)p[cb + d + 64]) << 16;
        p[cb + d]      = (unsigned short)f2bf1(x1.f * c - x2.f * sn);
        p[cb + d + 64] = (unsigned short)f2bf1(x2.f * c + x1.f * sn);
    }
}

// ---------------------------------------------------------------------------
// Flash attention, bf16, MFMA 16x16x32, XOR-swizzled LDS (conflict-free),
// double-buffered K/V with register prefetch -> ONE barrier per K-tile.
// 512 blocks, each does TWO q-tiles (jpair, 31-jpair) = uniform 33 KV-units.
// Structure locked by rounds 1/2/4/6 (all regressed): keep dbuf + (256,2),
// no split-KV, no XCD swizzle, no setprio, no defer-rescale.
// THIS round's change: BATCHED softmax reduction trees. The 4 r-rows'
// max/sum shuffle trees were serial (8 dependent-shuffle trees x 4 levels
// x ~35cy = ~1120 cy/tile of pure DS latency). Interleaving the 4
// independent trees level-by-level pipelines them (~4x latency cut) while
// executing the IDENTICAL ops in identical per-r order (bit-exact).
// qkv: [B*S, 3072] (q: h*128, k: 2048+kv*128, v: 2560+kv*128); o: [B*S, 2048].
// Swizzle keys: K/V chunk' = chunk ^ ((row + (row>>4)) & 7) at 16B-chunk
// granularity; P chunk' = chunk ^ ((row>>2) ^ ((row&3)<<1)).
// ---------------------------------------------------------------------------
__global__ __launch_bounds__(256, 2) void attn_mfma_kernel(
    const unsigned short* __restrict__ qkv, unsigned short* __restrict__ o)
{
    __shared__ unsigned int Ks_u[2][64 * 64];    // 2 x 16 KB
    __shared__ unsigned int Vs_u[2][128 * 32];   // 2 x 16 KB
    __shared__ unsigned short Ps[4][16 * 64];    // 8 KB, per-wave

    const int tid  = threadIdx.x;
    const int w    = tid >> 6;
    const int lane = tid & 63;
    const int quad = lane >> 4;
    const int l16  = lane & 15;
    const int jpair = blockIdx.x;   // 0..15
    const int h     = blockIdx.y;
    const int b     = blockIdx.z;
    const int kv    = h >> 2;       // G = 4

    const float k2 = 0.12752789744920764f;  // (1/sqrt(128)) * log2(e)

    const unsigned short* kbase = qkv + (size_t)b * SS * 3072 + 2048 + kv * 128;
    const unsigned short* vbase = kbase + 512;

    const int kc  = tid & 15;          // K chunk (8 dims)
    const int kp0 = tid >> 4;          // K row base 0..15
    const int vpp = tid >> 3;          // V pos-pair 0..31
    const int vd0 = (tid & 7) * 16;    // V d-segment base

    for (int pass = 0; pass < 2; ++pass) {
        const int qt = pass ? (QTILES - 1 - jpair) : jpair;
        const int q0 = qt * 64;

        // ---- Q A-frags ----
        short8 qf[4];
        {
            const unsigned short* qp = qkv + (size_t)(b * SS + q0 + w * 16 + l16) * 3072 + h * 128 + quad * 8;
#pragma unroll
            for (int ks = 0; ks < 4; ++ks)
                qf[ks] = *(const short8*)(qp + ks * 32);
        }

        // ---- prefetch tile 0 into regs ----
        uint4 kpre[4], vpa[2], vpb[2];
        {
            const unsigned short* kg = kbase + (size_t)kp0 * 3072 + kc * 8;
#pragma unroll
            for (int rr = 0; rr < 4; ++rr)
                kpre[rr] = *(const uint4*)(kg + (size_t)rr * 16 * 3072);
            const unsigned short* vg = vbase + (size_t)(2 * vpp) * 3072 + vd0;
            vpa[0] = *(const uint4*)(vg);
            vpa[1] = *(const uint4*)(vg + 8);
            vpb[0] = *(const uint4*)(vg + 3072);
            vpb[1] = *(const uint4*)(vg + 3072 + 8);
        }

        float m_r[4], l_r[4];
        f32x4 Oacc[8];
#pragma unroll
        for (int r = 0; r < 4; ++r) { m_r[r] = -1e30f; l_r[r] = 0.0f; }
#pragma unroll
        for (int ot = 0; ot < 8; ++ot) Oacc[ot] = (f32x4){0.f, 0.f, 0.f, 0.f};

        for (int t = 0; t <= qt; ++t) {
            const int buf = t & 1;
            unsigned int* Kb = Ks_u[buf];
            unsigned int* Vb = Vs_u[buf];

            // ---- staged regs -> LDS (swizzled, conflict-free) ----
#pragma unroll
            for (int rr = 0; rr < 4; ++rr) {
                int pos = kp0 + rr * 16;
                int key = (kp0 + rr) & 7;           // (pos + (pos>>4)) & 7
                *(uint4*)&Kb[pos * 64 + (kc ^ key) * 4] = kpre[rr];
            }
            {
                const unsigned int* pa = (const unsigned int*)vpa;
                const unsigned int* pb = (const unsigned int*)vpb;
#pragma unroll
                for (int j = 0; j < 8; ++j) {
                    unsigned lo = __builtin_amdgcn_perm(pb[j], pa[j], 0x05040100);
                    unsigned hi = __builtin_amdgcn_perm(pb[j], pa[j], 0x07060302);
                    int d0 = vd0 + 2 * j;
                    int g  = d0 >> 4;               // same for d0 and d0+1
                    int k0 = (d0 + g) & 7;
                    int k1 = (d0 + 1 + g) & 7;
                    Vb[d0 * 32 + (((vpp >> 2) ^ k0) & 7) * 4 + (vpp & 3)] = lo;
                    Vb[(d0 + 1) * 32 + (((vpp >> 2) ^ k1) & 7) * 4 + (vpp & 3)] = hi;
                }
            }

            // ---- prefetch tile t+1 (latency hidden under compute) ----
            if (t < qt) {
                const unsigned short* kg = kbase + (size_t)((t + 1) * 64 + kp0) * 3072 + kc * 8;
#pragma unroll
                for (int rr = 0; rr < 4; ++rr)
                    kpre[rr] = *(const uint4*)(kg + (size_t)rr * 16 * 3072);
                const unsigned short* vg = vbase + (size_t)((t + 1) * 64 + 2 * vpp) * 3072 + vd0;
                vpa[0] = *(const uint4*)(vg);
                vpa[1] = *(const uint4*)(vg + 8);
                vpb[0] = *(const uint4*)(vg + 3072);
                vpb[1] = *(const uint4*)(vg + 3072 + 8);
            }
            __syncthreads();

            // ---- S = Q @ K^T (16x64 per wave), raw scores ----
            f32x4 S[4];
#pragma unroll
            for (int ct = 0; ct < 4; ++ct) {
                f32x4 s = (f32x4){0.f, 0.f, 0.f, 0.f};
                const int row = ct * 16 + l16;
                const int key = (l16 + ct) & 7;     // (pos + (pos>>4)) & 7
#pragma unroll
                for (int ks = 0; ks < 4; ++ks) {
                    short8 kf = *(const short8*)&Kb[row * 64 + ((ks * 4 + quad) ^ key) * 4];
                    s = __builtin_amdgcn_mfma_f32_16x16x32_bf16(qf[ks], kf, s, 0, 0, 0);
                }
                S[ct] = s;
            }

            // ---- causal mask (diagonal tile only) ----
            if (t == qt) {
                const int rowloc = w * 16 + quad * 4;
#pragma unroll
                for (int ct = 0; ct < 4; ++ct)
#pragma unroll
                    for (int r = 0; r < 4; ++r)
                        if (ct * 16 + l16 > rowloc + r) S[ct][r] = -1e30f;
            }

            // ---- online softmax, BATCHED reduction trees ----
            // phase 1: per-row 3-op local max (independent across r)
            float c0[4];
#pragma unroll
            for (int r = 0; r < 4; ++r)
                c0[r] = fmaxf(fmaxf(S[0][r], S[1][r]), fmaxf(S[2][r], S[3][r]));
            // phase 2: 4 max trees interleaved level-by-level (pipelined DS)
#pragma unroll
            for (int st = 1; st <= 8; st <<= 1)
#pragma unroll
                for (int r = 0; r < 4; ++r)
                    c0[r] = fmaxf(c0[r], __shfl_xor(c0[r], st));
            // phase 3: m/alpha update + exp + P store (independent across r)
            float alpha[4], mh[4], rs[4];
#pragma unroll
            for (int r = 0; r < 4; ++r) {
                float mnew = fmaxf(m_r[r], c0[r]);
                alpha[r] = exp2f((m_r[r] - mnew) * k2);
                m_r[r] = mnew;
                mh[r] = mnew * k2;
                rs[r] = 0.0f;
            }
#pragma unroll
            for (int r = 0; r < 4; ++r) {
                const int prow = quad * 4 + r;
                const int pkey = (prow >> 2) ^ ((prow & 3) << 1);
#pragma unroll
                for (int ct = 0; ct < 4; ++ct) {
                    float p = exp2f(S[ct][r] * k2 - mh[r]);
                    rs[r] += p;
                    int chunk = ct * 2 + (l16 >> 3);
                    union { float f; unsigned u; } pu; pu.f = p;
                    Ps[w][prow * 64 + (chunk ^ pkey) * 8 + (l16 & 7)] =
                        (unsigned short)((pu.u + 0x8000u) >> 16);
                }
            }
            // phase 4: 4 sum trees interleaved level-by-level
#pragma unroll
            for (int st = 1; st <= 8; st <<= 1)
#pragma unroll
                for (int r = 0; r < 4; ++r)
                    rs[r] += __shfl_xor(rs[r], st);
            // phase 5: l update + Oacc rescale
#pragma unroll
            for (int r = 0; r < 4; ++r) {
                l_r[r] = l_r[r] * alpha[r] + rs[r];
#pragma unroll
                for (int ot = 0; ot < 8; ++ot) Oacc[ot][r] *= alpha[r];
            }

            // ---- O += P @ V ----
            {
                const int pkeyr = (l16 >> 2) ^ ((l16 & 3) << 1);
                short8 pf0 = *(const short8*)&Ps[w][l16 * 64 + (quad ^ pkeyr) * 8];
                short8 pf1 = *(const short8*)&Ps[w][l16 * 64 + ((4 + quad) ^ pkeyr) * 8];
#pragma unroll
                for (int ot = 0; ot < 8; ++ot) {
                    const int d = ot * 16 + l16;
                    const int vkey = (l16 + ot) & 7;    // (d + (d>>4)) & 7
                    short8 v0 = *(const short8*)&Vb[d * 32 + (quad ^ vkey) * 4];
                    Oacc[ot] = __builtin_amdgcn_mfma_f32_16x16x32_bf16(pf0, v0, Oacc[ot], 0, 0, 0);
                    short8 v1 = *(const short8*)&Vb[d * 32 + ((4 + quad) ^ vkey) * 4];
                    Oacc[ot] = __builtin_amdgcn_mfma_f32_16x16x32_bf16(pf1, v1, Oacc[ot], 0, 0, 0);
                }
            }
            // no tail barrier: next iteration writes the other buffer
        }

        // ---- epilogue: bf16 store to [B*S, 2048] ----
        float inv[4];
#pragma unroll
        for (int r = 0; r < 4; ++r) inv[r] = 1.0f / l_r[r];
        const int orow0 = q0 + w * 16 + quad * 4;
        unsigned short* ob = o + (size_t)(b * SS + orow0) * 2048 + h * 128 + l16;
#pragma unroll
        for (int r = 0; r < 4; ++r)
#pragma unroll
            for (int ot = 0; ot < 8; ++ot)
                ob[(size_t)r * 2048 + ot * 16] = (unsigned short)f2bf1(Oacc[ot][r] * inv[r]);

        __syncthreads();   // protect LDS buffers across pass boundary
    }
}

// ---------------------------------------------------------------------------
extern "C" void kernel_launch(void* const* d_in, const int* in_sizes, int n_in,
                              void* d_out, int out_size, void* d_ws, size_t ws_size,
                              hipStream_t stream)
{
    const float* x  = (const float*)d_in[0];
    const float* Wq = (const float*)d_in[1];
    const float* bq = (const float*)d_in[2];
    const float* Wk = (const float*)d_in[3];
    const float* bk = (const float*)d_in[4];
    const float* Wv = (const float*)d_in[5];
    const float* bv = (const float*)d_in[6];
    const float* Wo = (const float*)d_in[7];
    float* out = (float*)d_out;

    const int M = BB * SS;  // 4096
    char* wsb = (char*)d_ws;
    unsigned short* xb   = (unsigned short*)wsb;  wsb += (size_t)M * EE * 2;        // 16.8 MB
    unsigned short* wqkv = (unsigned short*)wsb;  wsb += (size_t)3072 * EE * 2;     // 12.6 MB
    unsigned short* wob  = (unsigned short*)wsb;  wsb += (size_t)EE * EE * 2;       //  8.4 MB
    unsigned short* qkvb = (unsigned short*)wsb;  wsb += (size_t)M * 3072 * 2;      // 25.2 MB
    unsigned short* abb  = (unsigned short*)wsb;  wsb += (size_t)M * 2048 * 2;      // 16.8 MB
    float* bqkv = (float*)wsb;                    wsb += 4096 * 4;                  // 16 KB (2560 used)
    float* rtab = (float*)wsb;                    // 1 MB: cos[2048*64] | sin[2048*64]

    // one fused conversion launch (x, Wq, Wk, Wv, Wo, biases, rope table)
    cvt_all_kernel<<<18947, 256, 0, stream>>>(x, Wq, Wk, Wv, Wo, bq, bk, bv,
                                              xb, wqkv, wob, bqkv, rtab);

    // fused QKV projection: [M,3072] = xb @ wqkv^T + bqkv (bf16 out)
    gemm_mfma_kernel<true><<<dim3(3072 / 128, M / 128), 256, 0, stream>>>(
        xb, wqkv, bqkv, qkvb, M, 3072, EE);

    // RoPE on q and k heads, table-based, one block per row
    rope_kernel<<<M, 256, 0, stream>>>(qkvb, rtab, rtab + 131072);

    // flash attention -> abb (bf16)
    attn_mfma_kernel<<<dim3(16, HH, BB), 256, 0, stream>>>(qkvb, abb);

    // output projection: out = abb @ wob^T (fp32 out)
    gemm_mfma_kernel<false><<<dim3(EE / 128, M / 128), 256, 0, stream>>>(
        abb, wob, nullptr, out, M, EE, 2048);
}

// Round 9
// 342.070 us; speedup vs baseline: 1.2542x; 1.0523x over previous
//
#include <hip/hip_runtime.h>
#include <hip/hip_bf16.h>
#include <math.h>

// Problem constants (QwenAttention: B=2,S=2048,E=2048,H=16,KV=4,D=128)
#define BB 2
#define SS 2048
#define EE 2048
#define HH 16
#define KVH 4
#define DD 128
#define QTILES 32   // S / 64

typedef short short8 __attribute__((ext_vector_type(8)));
typedef float f32x4 __attribute__((ext_vector_type(4)));

__device__ __forceinline__ unsigned int f2bf1(float x) {
    union { float f; unsigned int u; } v; v.f = x;
    return (v.u + 0x7FFFu + ((v.u >> 16) & 1u)) >> 16;  // RNE bf16
}
__device__ __forceinline__ unsigned int packbf(float a, float b) {
    return f2bf1(a) | (f2bf1(b) << 16);
}
// async global->LDS, 16B per lane; LDS dest = wave-uniform base + lane*16
__device__ __forceinline__ void gl_lds16(const void* g, void* l) {
    __builtin_amdgcn_global_load_lds(
        (const __attribute__((address_space(1))) unsigned int*)g,
        (__attribute__((address_space(3))) unsigned int*)l,
        16, 0, 0);
}

// ---------------------------------------------------------------------------
// Fused fp32->bf16 conversion of all inputs + bias concat + RoPE cos/sin
// table, one launch. Segments in float4 units: x | Wq | Wk | Wv | Wo |
// biases(fp32) | rope table (cos[2048][64], sin[2048][64] f32).
// ---------------------------------------------------------------------------
__global__ __launch_bounds__(256) void cvt_all_kernel(
    const float* __restrict__ x,  const float* __restrict__ Wq,
    const float* __restrict__ Wk, const float* __restrict__ Wv,
    const float* __restrict__ Wo, const float* __restrict__ bq,
    const float* __restrict__ bk, const float* __restrict__ bv,
    unsigned short* __restrict__ xb, unsigned short* __restrict__ wqkv,
    unsigned short* __restrict__ wob, float* __restrict__ bqkv,
    float* __restrict__ rtab)
{
    long id = (long)blockIdx.x * 256 + threadIdx.x;
    const float* src; unsigned short* dst; long j;
    if (id < 2097152)      { j = id;           src = x;  dst = xb; }
    else if (id < 3145728) { j = id - 2097152; src = Wq; dst = wqkv; }
    else if (id < 3407872) { j = id - 3145728; src = Wk; dst = wqkv + 4194304; }
    else if (id < 3670016) { j = id - 3407872; src = Wv; dst = wqkv + 5242880; }
    else if (id < 4718592) { j = id - 3670016; src = Wo; dst = wob; }
    else if (id < 4719360) {
        long c = (id - 4718592) * 4;
#pragma unroll
        for (int e = 0; e < 4; ++e) {
            long cc = c + e;
            bqkv[cc] = (cc < 2048) ? bq[cc] : (cc < 2560 ? bk[cc - 2048] : bv[cc - 2560]);
        }
        return;
    } else if (id < 4850432) {
        // rope table: one sincos per (s, d) entry
        long e = id - 4719360;            // 0 .. 131071
        int sg = (int)(e >> 6);           // position 0..2047
        int dg = (int)(e & 63);           // freq index 0..63
        float inv_freq = expf(-(float)dg * (logf(10000.0f) / 64.0f));
        float fr = (float)sg * inv_freq;
        rtab[e]          = cosf(fr);
        rtab[131072 + e] = sinf(fr);
        return;
    } else return;
    float4 f = ((const float4*)src)[j];
    ((uint2*)dst)[j] = make_uint2(packbf(f.x, f.y), packbf(f.z, f.w));
}

// ---------------------------------------------------------------------------
// bf16 MFMA GEMM: C[M,N] = A[M,K] @ W[N,K]^T + bias[N]
// 128x128 tile, 256 threads = 4 waves (2x2), 4x4 MFMA tiles per wave.
// THIS round: BK 32 -> 64. Halves K-steps (and the vmcnt(0)+lgkmcnt(0)
// barrier-drain events, the m97-structure's ~20% stall) for K=2048.
// BK=64 needs an LDS swizzle: unswizzled, the frag ds_read_b128 puts all
// 16 lanes of a quad-group in one 4-bank window (2x minimum rounds).
// Fix = attn's proven pattern: linear gl_lds dest + PRE-SWIZZLED global
// source col ((lane&7)^(lane>>3))*8 (dest row == lane>>3 mod 8) + XOR on
// the read chunk: chunk' = chunk ^ (row&7). Restores minimum 8 rounds.
// (r7 lesson: keep the epilogue simple -- no fused rope.)
// ---------------------------------------------------------------------------
template <bool OUT_BF16>
__global__ __launch_bounds__(256) void gemm_mfma_kernel(
    const unsigned short* __restrict__ A, const unsigned short* __restrict__ W,
    const float* __restrict__ bias, void* __restrict__ Cout,
    int M, int N, int K)
{
    __shared__ unsigned short As[128 * 64];
    __shared__ unsigned short Bs[128 * 64];

    const int tid  = threadIdx.x;
    const int w    = tid >> 6;
    const int lane = tid & 63;
    const int quad = lane >> 4;
    const int l16  = lane & 15;
    const int wr   = w >> 1, wc = w & 1;
    const int m0 = blockIdx.y * 128, n0 = blockIdx.x * 128;

    f32x4 acc[4][4];
#pragma unroll
    for (int i = 0; i < 4; ++i)
#pragma unroll
        for (int j = 0; j < 4; ++j) acc[i][j] = (f32x4){0.f, 0.f, 0.f, 0.f};

    // staging map: dest LDS row (within 32-row call-chunk) = w*8 + (lane>>3),
    // dest chunk = lane&7; source col pre-swizzled so LDS logical layout is
    // row-major with chunk' = chunk ^ (row&7); row&7 == lane>>3.
    const int scol = ((lane & 7) ^ (lane >> 3)) * 8;
    const unsigned short* Ag = A + (size_t)(m0 + w * 8 + (lane >> 3)) * K + scol;
    const unsigned short* Wg = W + (size_t)(n0 + w * 8 + (lane >> 3)) * K + scol;
    unsigned short* AsB = &As[(w * 8) * 64];
    unsigned short* BsB = &Bs[(w * 8) * 64];

    const int rkey = (l16 & 7) * 8;   // read-side XOR key (in shorts)

    for (int k0 = 0; k0 < K; k0 += 64) {
#pragma unroll
        for (int c = 0; c < 4; ++c) {
            gl_lds16(Ag + k0 + (size_t)(32 * c) * K, AsB + 32 * c * 64);
            gl_lds16(Wg + k0 + (size_t)(32 * c) * K, BsB + 32 * c * 64);
        }
        __syncthreads();

#pragma unroll
        for (int ks = 0; ks < 2; ++ks) {
            short8 a_f[4], b_f[4];
#pragma unroll
            for (int i = 0; i < 4; ++i)
                a_f[i] = *(const short8*)&As[(wr * 64 + i * 16 + l16) * 64 + (((ks * 4 + quad) * 8) ^ rkey)];
#pragma unroll
            for (int j = 0; j < 4; ++j)
                b_f[j] = *(const short8*)&Bs[(wc * 64 + j * 16 + l16) * 64 + (((ks * 4 + quad) * 8) ^ rkey)];
#pragma unroll
            for (int i = 0; i < 4; ++i)
#pragma unroll
                for (int j = 0; j < 4; ++j)
                    acc[i][j] = __builtin_amdgcn_mfma_f32_16x16x32_bf16(a_f[i], b_f[j], acc[i][j], 0, 0, 0);
        }
        __syncthreads();
    }

    float bj[4];
#pragma unroll
    for (int j = 0; j < 4; ++j)
        bj[j] = bias ? bias[n0 + wc * 64 + j * 16 + l16] : 0.0f;
#pragma unroll
    for (int i = 0; i < 4; ++i) {
#pragma unroll
        for (int r = 0; r < 4; ++r) {
            size_t row = m0 + wr * 64 + i * 16 + quad * 4 + r;
#pragma unroll
            for (int j = 0; j < 4; ++j) {
                size_t col = n0 + wc * 64 + j * 16 + l16;
                float val = acc[i][j][r] + bj[j];
                if (OUT_BF16)
                    ((unsigned short*)Cout)[row * N + col] = (unsigned short)f2bf1(val);
                else
                    ((float*)Cout)[row * N + col] = val;
            }
        }
    }
}

// ---------------------------------------------------------------------------
// RoPE on bf16 qkv buffer [M, 3072] (q cols 0..2047, k cols 2048..2559).
// Table-based: cos/sin from precomputed [2048][64] f32 tables (no device
// trig in hot path). One block per row, 256 threads x 5 pairs.
// ---------------------------------------------------------------------------
__global__ __launch_bounds__(256) void rope_kernel(
    unsigned short* __restrict__ qkv,
    const float* __restrict__ ctab, const float* __restrict__ stab)
{
    const int m = blockIdx.x;          // row in [0, B*S)
    const int s = m & (SS - 1);
    unsigned short* p = qkv + (size_t)m * 3072;
    const float* cr = ctab + s * 64;
    const float* sr = stab + s * 64;
#pragma unroll
    for (int it = 0; it < 5; ++it) {
        int idx = threadIdx.x + it * 256;   // 0..1279 : 20 heads x 64 pairs
        int hh = idx >> 6;
        int d  = idx & 63;
        int cb = (hh < 16) ? hh * 128 : 2048 + (hh - 16) * 128;
        float c  = cr[d];
        float sn = sr[d];
        union { unsigned int u; float f; } x1, x2;
        x1.u = ((unsigned int)p[cb + d]) << 16;
        x2.u = ((unsigned int)p[cb + d + 64]) << 16;
        p[cb + d]      = (unsigned short)f2bf1(x1.f * c - x2.f * sn);
        p[cb + d + 64] = (unsigned short)f2bf1(x2.f * c + x1.f * sn);
    }
}

// ---------------------------------------------------------------------------
// Flash attention, bf16, MFMA 16x16x32, XOR-swizzled LDS (conflict-free),
// double-buffered K/V with register prefetch -> ONE barrier per K-tile.
// 512 blocks, each does TWO q-tiles (jpair, 31-jpair) = uniform 33 KV-units.
// Structure locked by rounds 1/2/4/6/8 (all null or regressed): keep dbuf +
// (256,2); no split-KV, no XCD swizzle, no setprio, no defer-rescale; the
// batched softmax trees (r8) are kept (neutral, no cost).
// qkv: [B*S, 3072] (q: h*128, k: 2048+kv*128, v: 2560+kv*128); o: [B*S, 2048].
// Swizzle keys: K/V chunk' = chunk ^ ((row + (row>>4)) & 7) at 16B-chunk
// granularity; P chunk' = chunk ^ ((row>>2) ^ ((row&3)<<1)).
// ---------------------------------------------------------------------------
__global__ __launch_bounds__(256, 2) void attn_mfma_kernel(
    const unsigned short* __restrict__ qkv, unsigned short* __restrict__ o)
{
    __shared__ unsigned int Ks_u[2][64 * 64];    // 2 x 16 KB
    __shared__ unsigned int Vs_u[2][128 * 32];   // 2 x 16 KB
    __shared__ unsigned short Ps[4][16 * 64];    // 8 KB, per-wave

    const int tid  = threadIdx.x;
    const int w    = tid >> 6;
    const int lane = tid & 63;
    const int quad = lane >> 4;
    const int l16  = lane & 15;
    const int jpair = blockIdx.x;   // 0..15
    const int h     = blockIdx.y;
    const int b     = blockIdx.z;
    const int kv    = h >> 2;       // G = 4

    const float k2 = 0.12752789744920764f;  // (1/sqrt(128)) * log2(e)

    const unsigned short* kbase = qkv + (size_t)b * SS * 3072 + 2048 + kv * 128;
    const unsigned short* vbase = kbase + 512;

    const int kc  = tid & 15;          // K chunk (8 dims)
    const int kp0 = tid >> 4;          // K row base 0..15
    const int vpp = tid >> 3;          // V pos-pair 0..31
    const int vd0 = (tid & 7) * 16;    // V d-segment base

    for (int pass = 0; pass < 2; ++pass) {
        const int qt = pass ? (QTILES - 1 - jpair) : jpair;
        const int q0 = qt * 64;

        // ---- Q A-frags ----
        short8 qf[4];
        {
            const unsigned short* qp = qkv + (size_t)(b * SS + q0 + w * 16 + l16) * 3072 + h * 128 + quad * 8;
#pragma unroll
            for (int ks = 0; ks < 4; ++ks)
                qf[ks] = *(const short8*)(qp + ks * 32);
        }

        // ---- prefetch tile 0 into regs ----
        uint4 kpre[4], vpa[2], vpb[2];
        {
            const unsigned short* kg = kbase + (size_t)kp0 * 3072 + kc * 8;
#pragma unroll
            for (int rr = 0; rr < 4; ++rr)
                kpre[rr] = *(const uint4*)(kg + (size_t)rr * 16 * 3072);
            const unsigned short* vg = vbase + (size_t)(2 * vpp) * 3072 + vd0;
            vpa[0] = *(const uint4*)(vg);
            vpa[1] = *(const uint4*)(vg + 8);
            vpb[0] = *(const uint4*)(vg + 3072);
            vpb[1] = *(const uint4*)(vg + 3072 + 8);
        }

        float m_r[4], l_r[4];
        f32x4 Oacc[8];
#pragma unroll
        for (int r = 0; r < 4; ++r) { m_r[r] = -1e30f; l_r[r] = 0.0f; }
#pragma unroll
        for (int ot = 0; ot < 8; ++ot) Oacc[ot] = (f32x4){0.f, 0.f, 0.f, 0.f};

        for (int t = 0; t <= qt; ++t) {
            const int buf = t & 1;
            unsigned int* Kb = Ks_u[buf];
            unsigned int* Vb = Vs_u[buf];

            // ---- staged regs -> LDS (swizzled, conflict-free) ----
#pragma unroll
            for (int rr = 0; rr < 4; ++rr) {
                int pos = kp0 + rr * 16;
                int key = (kp0 + rr) & 7;           // (pos + (pos>>4)) & 7
                *(uint4*)&Kb[pos * 64 + (kc ^ key) * 4] = kpre[rr];
            }
            {
                const unsigned int* pa = (const unsigned int*)vpa;
                const unsigned int* pb = (const unsigned int*)vpb;
#pragma unroll
                for (int j = 0; j < 8; ++j) {
                    unsigned lo = __builtin_amdgcn_perm(pb[j], pa[j], 0x05040100);
                    unsigned hi = __builtin_amdgcn_perm(pb[j], pa[j], 0x07060302);
                    int d0 = vd0 + 2 * j;
                    int g  = d0 >> 4;               // same for d0 and d0+1
                    int k0 = (d0 + g) & 7;
                    int k1 = (d0 + 1 + g) & 7;
                    Vb[d0 * 32 + (((vpp >> 2) ^ k0) & 7) * 4 + (vpp & 3)] = lo;
                    Vb[(d0 + 1) * 32 + (((vpp >> 2) ^ k1) & 7) * 4 + (vpp & 3)] = hi;
                }
            }

            // ---- prefetch tile t+1 (latency hidden under compute) ----
            if (t < qt) {
                const unsigned short* kg = kbase + (size_t)((t + 1) * 64 + kp0) * 3072 + kc * 8;
#pragma unroll
                for (int rr = 0; rr < 4; ++rr)
                    kpre[rr] = *(const uint4*)(kg + (size_t)rr * 16 * 3072);
                const unsigned short* vg = vbase + (size_t)((t + 1) * 64 + 2 * vpp) * 3072 + vd0;
                vpa[0] = *(const uint4*)(vg);
                vpa[1] = *(const uint4*)(vg + 8);
                vpb[0] = *(const uint4*)(vg + 3072);
                vpb[1] = *(const uint4*)(vg + 3072 + 8);
            }
            __syncthreads();

            // ---- S = Q @ K^T (16x64 per wave), raw scores ----
            f32x4 S[4];
#pragma unroll
            for (int ct = 0; ct < 4; ++ct) {
                f32x4 s = (f32x4){0.f, 0.f, 0.f, 0.f};
                const int row = ct * 16 + l16;
                const int key = (l16 + ct) & 7;     // (pos + (pos>>4)) & 7
#pragma unroll
                for (int ks = 0; ks < 4; ++ks) {
                    short8 kf = *(const short8*)&Kb[row * 64 + ((ks * 4 + quad) ^ key) * 4];
                    s = __builtin_amdgcn_mfma_f32_16x16x32_bf16(qf[ks], kf, s, 0, 0, 0);
                }
                S[ct] = s;
            }

            // ---- causal mask (diagonal tile only) ----
            if (t == qt) {
                const int rowloc = w * 16 + quad * 4;
#pragma unroll
                for (int ct = 0; ct < 4; ++ct)
#pragma unroll
                    for (int r = 0; r < 4; ++r)
                        if (ct * 16 + l16 > rowloc + r) S[ct][r] = -1e30f;
            }

            // ---- online softmax, batched reduction trees (r8, kept) ----
            float c0[4];
#pragma unroll
            for (int r = 0; r < 4; ++r)
                c0[r] = fmaxf(fmaxf(S[0][r], S[1][r]), fmaxf(S[2][r], S[3][r]));
#pragma unroll
            for (int st = 1; st <= 8; st <<= 1)
#pragma unroll
                for (int r = 0; r < 4; ++r)
                    c0[r] = fmaxf(c0[r], __shfl_xor(c0[r], st));
            float alpha[4], mh[4], rs[4];
#pragma unroll
            for (int r = 0; r < 4; ++r) {
                float mnew = fmaxf(m_r[r], c0[r]);
                alpha[r] = exp2f((m_r[r] - mnew) * k2);
                m_r[r] = mnew;
                mh[r] = mnew * k2;
                rs[r] = 0.0f;
            }
#pragma unroll
            for (int r = 0; r < 4; ++r) {
                const int prow = quad * 4 + r;
                const int pkey = (prow >> 2) ^ ((prow & 3) << 1);
#pragma unroll
                for (int ct = 0; ct < 4; ++ct) {
                    float p = exp2f(S[ct][r] * k2 - mh[r]);
                    rs[r] += p;
                    int chunk = ct * 2 + (l16 >> 3);
                    union { float f; unsigned u; } pu; pu.f = p;
                    Ps[w][prow * 64 + (chunk ^ pkey) * 8 + (l16 & 7)] =
                        (unsigned short)((pu.u + 0x8000u) >> 16);
                }
            }
#pragma unroll
            for (int st = 1; st <= 8; st <<= 1)
#pragma unroll
                for (int r = 0; r < 4; ++r)
                    rs[r] += __shfl_xor(rs[r], st);
#pragma unroll
            for (int r = 0; r < 4; ++r) {
                l_r[r] = l_r[r] * alpha[r] + rs[r];
#pragma unroll
                for (int ot = 0; ot < 8; ++ot) Oacc[ot][r] *= alpha[r];
            }

            // ---- O += P @ V ----
            {
                const int pkeyr = (l16 >> 2) ^ ((l16 & 3) << 1);
                short8 pf0 = *(const short8*)&Ps[w][l16 * 64 + (quad ^ pkeyr) * 8];
                short8 pf1 = *(const short8*)&Ps[w][l16 * 64 + ((4 + quad) ^ pkeyr) * 8];
#pragma unroll
                for (int ot = 0; ot < 8; ++ot) {
                    const int d = ot * 16 + l16;
                    const int vkey = (l16 + ot) & 7;    // (d + (d>>4)) & 7
                    short8 v0 = *(const short8*)&Vb[d * 32 + (quad ^ vkey) * 4];
                    Oacc[ot] = __builtin_amdgcn_mfma_f32_16x16x32_bf16(pf0, v0, Oacc[ot], 0, 0, 0);
                    short8 v1 = *(const short8*)&Vb[d * 32 + ((4 + quad) ^ vkey) * 4];
                    Oacc[ot] = __builtin_amdgcn_mfma_f32_16x16x32_bf16(pf1, v1, Oacc[ot], 0, 0, 0);
                }
            }
            // no tail barrier: next iteration writes the other buffer
        }

        // ---- epilogue: bf16 store to [B*S, 2048] ----
        float inv[4];
#pragma unroll
        for (int r = 0; r < 4; ++r) inv[r] = 1.0f / l_r[r];
        const int orow0 = q0 + w * 16 + quad * 4;
        unsigned short* ob = o + (size_t)(b * SS + orow0) * 2048 + h * 128 + l16;
#pragma unroll
        for (int r = 0; r < 4; ++r)
#pragma unroll
            for (int ot = 0; ot < 8; ++ot)
                ob[(size_t)r * 2048 + ot * 16] = (unsigned short)f2bf1(Oacc[ot][r] * inv[r]);

        __syncthreads();   // protect LDS buffers across pass boundary
    }
}

// ---------------------------------------------------------------------------
extern "C" void kernel_launch(void* const* d_in, const int* in_sizes, int n_in,
                              void* d_out, int out_size, void* d_ws, size_t ws_size,
                              hipStream_t stream)
{
    const float* x  = (const float*)d_in[0];
    const float* Wq = (const float*)d_in[1];
    const float* bq = (const float*)d_in[2];
    const float* Wk = (const float*)d_in[3];
    const float* bk = (const float*)d_in[4];
    const float* Wv = (const float*)d_in[5];
    const float* bv = (const float*)d_in[6];
    const float* Wo = (const float*)d_in[7];
    float* out = (float*)d_out;

    const int M = BB * SS;  // 4096
    char* wsb = (char*)d_ws;
    unsigned short* xb   = (unsigned short*)wsb;  wsb += (size_t)M * EE * 2;        // 16.8 MB
    unsigned short* wqkv = (unsigned short*)wsb;  wsb += (size_t)3072 * EE * 2;     // 12.6 MB
    unsigned short* wob  = (unsigned short*)wsb;  wsb += (size_t)EE * EE * 2;       //  8.4 MB
    unsigned short* qkvb = (unsigned short*)wsb;  wsb += (size_t)M * 3072 * 2;      // 25.2 MB
    unsigned short* abb  = (unsigned short*)wsb;  wsb += (size_t)M * 2048 * 2;      // 16.8 MB
    float* bqkv = (float*)wsb;                    wsb += 4096 * 4;                  // 16 KB (2560 used)
    float* rtab = (float*)wsb;                    // 1 MB: cos[2048*64] | sin[2048*64]

    // one fused conversion launch (x, Wq, Wk, Wv, Wo, biases, rope table)
    cvt_all_kernel<<<18947, 256, 0, stream>>>(x, Wq, Wk, Wv, Wo, bq, bk, bv,
                                              xb, wqkv, wob, bqkv, rtab);

    // fused QKV projection: [M,3072] = xb @ wqkv^T + bqkv (bf16 out)
    gemm_mfma_kernel<true><<<dim3(3072 / 128, M / 128), 256, 0, stream>>>(
        xb, wqkv, bqkv, qkvb, M, 3072, EE);

    // RoPE on q and k heads, table-based, one block per row
    rope_kernel<<<M, 256, 0, stream>>>(qkvb, rtab, rtab + 131072);

    // flash attention -> abb (bf16)
    attn_mfma_kernel<<<dim3(16, HH, BB), 256, 0, stream>>>(qkvb, abb);

    // output projection: out = abb @ wob^T (fp32 out)
    gemm_mfma_kernel<false><<<dim3(EE / 128, M / 128), 256, 0, stream>>>(
        abb, wob, nullptr, out, M, EE, 2048);
}